// Round 1
// baseline (3145.823 us; speedup 1.0000x reference)
//
#include <hip/hip_runtime.h>
#include <hip/hip_bf16.h>
#include <math.h>

#define DIM 128
#define TOPK 128
#define CAP 4096

__device__ __forceinline__ unsigned f2k(float f) {
    unsigned b = __float_as_uint(f);
    return (b & 0x80000000u) ? ~b : (b | 0x80000000u);
}

__global__ void k_pnorm(const float* __restrict__ p, float* __restrict__ pinv) {
    __shared__ float s[DIM];
    int t = threadIdx.x;
    float v = p[t];
    s[t] = v * v;
    __syncthreads();
    for (int off = 64; off > 0; off >>= 1) {
        if (t < off) s[t] += s[t + off];
        __syncthreads();
    }
    if (t == 0) pinv[0] = 1.0f / sqrtf(s[0]);
}

// wave (64 lanes) per node, float2 per lane
__global__ void k_score(const float* __restrict__ x, const float* __restrict__ p,
                        const float* __restrict__ pinv, float* __restrict__ score, int n) {
    int lane = threadIdx.x & 63;
    int node = blockIdx.x * 4 + (threadIdx.x >> 6);
    if (node >= n) return;
    const float2* x2 = (const float2*)(x) + (size_t)node * 64;
    const float2* p2 = (const float2*)p;
    float2 a = x2[lane], b = p2[lane];
    float acc = a.x * b.x + a.y * b.y;
#pragma unroll
    for (int m = 32; m >= 1; m >>= 1) acc += __shfl_xor(acc, m, 64);
    if (lane == 0) score[node] = acc * pinv[0];
}

__global__ void k_zero(unsigned* __restrict__ hist, unsigned* __restrict__ counter) {
    int i = blockIdx.x * blockDim.x + threadIdx.x;
    if (i < 65536) hist[i] = 0u;
    if (i == 0) counter[0] = 0u;
}

__global__ void k_hist(const float* __restrict__ score, unsigned* __restrict__ hist, int n) {
    int i = blockIdx.x * blockDim.x + threadIdx.x;
    if (i < n) atomicAdd(&hist[f2k(score[i]) >> 16], 1u);
}

// find bin b* with cnt_above(b*) < k <= cnt_above(b*) + hist[b*]
__global__ void k_findbin(const unsigned* __restrict__ hist, unsigned* __restrict__ binfo, int k) {
    __shared__ unsigned csum[1024];
    int t = threadIdx.x;
    unsigned s = 0;
    for (int j = 0; j < 64; ++j) s += hist[t * 64 + j];
    unsigned mysum = s;
    csum[t] = s;
    __syncthreads();
    for (int off = 1; off < 1024; off <<= 1) {
        unsigned v = (t + off < 1024) ? csum[t + off] : 0u;
        __syncthreads();
        csum[t] += v;
        __syncthreads();
    }
    (void)mysum;
    unsigned run = (t + 1 < 1024) ? csum[t + 1] : 0u;   // count in bins > t*64+63
    for (int j = 63; j >= 0; --j) {
        unsigned h = hist[t * 64 + j];
        if (h > 0u && run < (unsigned)k && run + h >= (unsigned)k) {
            binfo[0] = (unsigned)(t * 64 + j);
            binfo[1] = run;
        }
        run += h;
    }
}

__global__ void k_collect(const float* __restrict__ score, const unsigned* __restrict__ binfo,
                          unsigned* __restrict__ counter, float* __restrict__ cval,
                          int* __restrict__ cidx, int n) {
    int i = blockIdx.x * blockDim.x + threadIdx.x;
    if (i >= n) return;
    float s = score[i];
    if ((f2k(s) >> 16) >= binfo[0]) {
        unsigned pos = atomicAdd(counter, 1u);
        if (pos < CAP) { cval[pos] = s; cidx[pos] = i; }
    }
}

// exact top-k, sorted desc, ties -> lower index (matches jax.lax.top_k)
__global__ void k_select(const float* __restrict__ cval, const int* __restrict__ cidx,
                         const unsigned* __restrict__ counter, int* __restrict__ perm,
                         float* __restrict__ vals, int k) {
    __shared__ float sv[CAP];
    __shared__ int si[CAP];
    __shared__ float rv[256];
    __shared__ int ri[256];
    __shared__ int rp[256];
    int t = threadIdx.x;
    unsigned cnt = counter[0];
    int m = (cnt < (unsigned)CAP) ? (int)cnt : CAP;
    for (int i = t; i < m; i += 256) { sv[i] = cval[i]; si[i] = cidx[i]; }
    __syncthreads();
    for (int kk = 0; kk < k; ++kk) {
        float bv = -INFINITY; int bi = 0x7fffffff; int bp = -1;
        for (int i = t; i < m; i += 256) {
            float v = sv[i]; int id = si[i];
            if (v > bv || (v == bv && id < bi)) { bv = v; bi = id; bp = i; }
        }
        rv[t] = bv; ri[t] = bi; rp[t] = bp;
        __syncthreads();
        for (int off = 128; off > 0; off >>= 1) {
            if (t < off) {
                float v2 = rv[t + off]; int i2 = ri[t + off];
                if (v2 > rv[t] || (v2 == rv[t] && i2 < ri[t])) {
                    rv[t] = v2; ri[t] = i2; rp[t] = rp[t + off];
                }
            }
            __syncthreads();
        }
        if (t == 0) {
            perm[kk] = ri[0];
            vals[kk] = rv[0];
            if (rp[0] >= 0) sv[rp[0]] = -INFINITY;
        }
        __syncthreads();
    }
}

__global__ void k_xtilde(const float* __restrict__ x, const int* __restrict__ perm,
                         const float* __restrict__ vals, float* __restrict__ xt) {
    int i = blockIdx.x, c = threadIdx.x;
    xt[i * DIM + c] = x[(size_t)perm[i] * DIM + c] * tanhf(vals[i]);
}

__global__ void k_gru(const float* __restrict__ xt, const float* __restrict__ W0,
                      const float* __restrict__ w_ih, const float* __restrict__ w_hh,
                      const float* __restrict__ b_ih, const float* __restrict__ b_hh,
                      float* __restrict__ W) {
    __shared__ float sx[DIM], sh[DIM];
    int i = blockIdx.x, c = threadIdx.x;
    sx[c] = xt[i * DIM + c];
    sh[c] = W0[i * DIM + c];
    __syncthreads();
    float gr = b_ih[c], gz = b_ih[DIM + c], gn = b_ih[2 * DIM + c];
    float hr = b_hh[c], hz = b_hh[DIM + c], hn = b_hh[2 * DIM + c];
    const float* wr = w_ih + (size_t)c * DIM;
    const float* wz = w_ih + (size_t)(DIM + c) * DIM;
    const float* wn = w_ih + (size_t)(2 * DIM + c) * DIM;
    const float* ur = w_hh + (size_t)c * DIM;
    const float* uz = w_hh + (size_t)(DIM + c) * DIM;
    const float* un = w_hh + (size_t)(2 * DIM + c) * DIM;
    for (int d = 0; d < DIM; ++d) {
        float xd = sx[d], hd = sh[d];
        gr += xd * wr[d]; gz += xd * wz[d]; gn += xd * wn[d];
        hr += hd * ur[d]; hz += hd * uz[d]; hn += hd * un[d];
    }
    float r = 1.0f / (1.0f + expf(-(gr + hr)));
    float z = 1.0f / (1.0f + expf(-(gz + hz)));
    float nn = tanhf(gn + r * hn);
    W[i * DIM + c] = (1.0f - z) * nn + z * sh[c];
}

__global__ void k_deg_init(float* __restrict__ deg, int n) {
    int i = blockIdx.x * blockDim.x + threadIdx.x;
    if (i < n) deg[i] = 1.0f;   // self-loop weight
}

__global__ void k_deg(const int* __restrict__ ei, const float* __restrict__ ew,
                      float* __restrict__ deg, int ne) {
    int e = blockIdx.x * blockDim.x + threadIdx.x;
    if (e < ne) atomicAdd(&deg[ei[ne + e]], ew[e]);
}

__global__ void k_dinv(float* __restrict__ deg, int n) {
    int i = blockIdx.x * blockDim.x + threadIdx.x;
    if (i < n) {
        float v = deg[i];
        deg[i] = (v > 0.0f) ? (1.0f / sqrtf(v)) : 0.0f;
    }
}

// xw = x @ W ; 64x64 block tile, 4x4 per thread, x stored transposed [k][r] in LDS
__global__ __launch_bounds__(256) void k_xw(const float* __restrict__ x,
                                            const float* __restrict__ W,
                                            float* __restrict__ xw, int n) {
    __shared__ float xsT[DIM * 64];  // [k][r]  32KB
    __shared__ float wls[DIM * 64];  // [k][c]  32KB
    int t = threadIdx.x;
    int r0 = blockIdx.x * 64;
    int c0 = blockIdx.y * 64;
    const float4* W4 = (const float4*)W;
#pragma unroll
    for (int it = 0; it < 8; ++it) {
        int id = t + it * 256;
        int k = id >> 4, c4 = id & 15;
        float4 w = W4[k * 32 + (c0 >> 2) + c4];
        *((float4*)&wls[k * 64 + c4 * 4]) = w;
    }
#pragma unroll
    for (int it = 0; it < 8; ++it) {
        int id = t + it * 256;
        int r = id & 63, k4 = id >> 6;
        int row = r0 + r; if (row >= n) row = n - 1;
        float4 v = *((const float4*)&x[(size_t)row * DIM + k4 * 4]);
        xsT[(k4 * 4 + 0) * 64 + r] = v.x;
        xsT[(k4 * 4 + 1) * 64 + r] = v.y;
        xsT[(k4 * 4 + 2) * 64 + r] = v.z;
        xsT[(k4 * 4 + 3) * 64 + r] = v.w;
    }
    __syncthreads();
    int tc = t & 15, tr = t >> 4;
    float acc[4][4];
#pragma unroll
    for (int i = 0; i < 4; ++i)
#pragma unroll
        for (int j = 0; j < 4; ++j) acc[i][j] = 0.0f;
#pragma unroll 4
    for (int k = 0; k < DIM; ++k) {
        float4 xa = *((const float4*)&xsT[k * 64 + tr * 4]);
        float4 wa = *((const float4*)&wls[k * 64 + tc * 4]);
        float xv[4] = {xa.x, xa.y, xa.z, xa.w};
        float wv[4] = {wa.x, wa.y, wa.z, wa.w};
#pragma unroll
        for (int i = 0; i < 4; ++i)
#pragma unroll
            for (int j = 0; j < 4; ++j) acc[i][j] += xv[i] * wv[j];
    }
#pragma unroll
    for (int i = 0; i < 4; ++i) {
        int row = r0 + tr * 4 + i;
        if (row < n) {
            float4 o = {acc[i][0], acc[i][1], acc[i][2], acc[i][3]};
            *((float4*)&xw[(size_t)row * DIM + c0 + tc * 4]) = o;
        }
    }
}

// agg[i] = xw[i] * dinv[i]^2   (self-loop term)
__global__ void k_agg_init(const float* __restrict__ xw, const float* __restrict__ dinv,
                           float* __restrict__ agg, int n) {
    int i = blockIdx.x * blockDim.x + threadIdx.x;   // float4 index
    if (i >= n * 32) return;
    int node = i >> 5;
    float dd = dinv[node]; dd *= dd;
    float4 v = ((const float4*)xw)[i];
    float4 o = {v.x * dd, v.y * dd, v.z * dd, v.w * dd};
    ((float4*)agg)[i] = o;
}

// 32 threads per edge, float4 gather + 4 atomics each
__global__ void k_scatter(const float* __restrict__ xw, const float* __restrict__ dinv,
                          const int* __restrict__ ei, const float* __restrict__ ew,
                          float* __restrict__ agg, int ne) {
    int gid = blockIdx.x * blockDim.x + threadIdx.x;
    int e = gid >> 5, lane = gid & 31;
    if (e >= ne) return;
    int r = ei[e], c = ei[ne + e];
    float nrm = dinv[r] * ew[e] * dinv[c];
    float4 v = ((const float4*)xw)[(size_t)r * 32 + lane];
    float* dst = agg + (size_t)c * DIM + lane * 4;
    atomicAdd(dst + 0, v.x * nrm);
    atomicAdd(dst + 1, v.y * nrm);
    atomicAdd(dst + 2, v.z * nrm);
    atomicAdd(dst + 3, v.w * nrm);
}

__global__ void k_head(const float* __restrict__ agg, const float* __restrict__ w_lin,
                       const float* __restrict__ b_lin, float* __restrict__ out, int n) {
    int lane = threadIdx.x & 63;
    int node = blockIdx.x * 4 + (threadIdx.x >> 6);
    if (node >= n) return;
    const float2* a2 = (const float2*)(agg) + (size_t)node * 64;
    const float2* w2 = (const float2*)w_lin;
    float2 a = a2[lane], w = w2[lane];
    float acc = fmaxf(a.x, 0.0f) * w.x + fmaxf(a.y, 0.0f) * w.y;
#pragma unroll
    for (int m = 32; m >= 1; m >>= 1) acc += __shfl_xor(acc, m, 64);
    if (lane == 0) out[node] = acc + b_lin[0];
}

extern "C" void kernel_launch(void* const* d_in, const int* in_sizes, int n_in,
                              void* d_out, int out_size, void* d_ws, size_t ws_size,
                              hipStream_t stream) {
    const float* x     = (const float*)d_in[0];
    const int*   ei    = (const int*)d_in[1];
    const float* ew    = (const float*)d_in[2];
    const float* p     = (const float*)d_in[3];
    const float* W0    = (const float*)d_in[4];
    const float* w_ih  = (const float*)d_in[5];
    const float* w_hh  = (const float*)d_in[6];
    const float* b_ih  = (const float*)d_in[7];
    const float* b_hh  = (const float*)d_in[8];
    const float* w_lin = (const float*)d_in[9];
    const float* b_lin = (const float*)d_in[10];
    float* out = (float*)d_out;
    int n  = in_sizes[0] / DIM;
    int ne = in_sizes[2];
    (void)n_in; (void)out_size; (void)ws_size;

    char* base = (char*)d_ws;
    size_t o = 0;
    auto alloc = [&](size_t b) { size_t r = o; o += (b + 255) & ~(size_t)255; return r; };
    float*    score   = (float*)(base + alloc((size_t)n * 4));
    unsigned* hist    = (unsigned*)(base + alloc(65536 * 4));
    unsigned* counter = (unsigned*)(base + alloc(256));
    unsigned* binfo   = (unsigned*)(base + alloc(256));
    float*    cval    = (float*)(base + alloc((size_t)CAP * 4));
    int*      cidx    = (int*)(base + alloc((size_t)CAP * 4));
    int*      perm    = (int*)(base + alloc(TOPK * 4));
    float*    vals    = (float*)(base + alloc(TOPK * 4));
    float*    pinv    = (float*)(base + alloc(256));
    float*    xt      = (float*)(base + alloc(DIM * DIM * 4));
    float*    Wm      = (float*)(base + alloc(DIM * DIM * 4));
    float*    dinv    = (float*)(base + alloc((size_t)n * 4));
    float*    xw      = (float*)(base + alloc((size_t)n * DIM * 4));
    float*    agg     = (float*)(base + alloc((size_t)n * DIM * 4));

    k_pnorm<<<1, DIM, 0, stream>>>(p, pinv);
    k_score<<<(n + 3) / 4, 256, 0, stream>>>(x, p, pinv, score, n);
    k_zero<<<(65537 + 255) / 256, 256, 0, stream>>>(hist, counter);
    k_hist<<<(n + 255) / 256, 256, 0, stream>>>(score, hist, n);
    k_findbin<<<1, 1024, 0, stream>>>(hist, binfo, TOPK);
    k_collect<<<(n + 255) / 256, 256, 0, stream>>>(score, binfo, counter, cval, cidx, n);
    k_select<<<1, 256, 0, stream>>>(cval, cidx, counter, perm, vals, TOPK);
    k_xtilde<<<DIM, DIM, 0, stream>>>(x, perm, vals, xt);
    k_gru<<<DIM, DIM, 0, stream>>>(xt, W0, w_ih, w_hh, b_ih, b_hh, Wm);
    k_deg_init<<<(n + 255) / 256, 256, 0, stream>>>(dinv, n);
    k_deg<<<(ne + 255) / 256, 256, 0, stream>>>(ei, ew, dinv, ne);
    k_dinv<<<(n + 255) / 256, 256, 0, stream>>>(dinv, n);
    dim3 gxw((n + 63) / 64, 2);
    k_xw<<<gxw, 256, 0, stream>>>(x, Wm, xw, n);
    k_agg_init<<<((n * 32) + 255) / 256, 256, 0, stream>>>(xw, dinv, agg, n);
    long long sc_threads = (long long)ne * 32;
    k_scatter<<<(int)((sc_threads + 255) / 256), 256, 0, stream>>>(xw, dinv, ei, ew, agg, ne);
    k_head<<<(n + 3) / 4, 256, 0, stream>>>(agg, w_lin, b_lin, out, n);
}

// Round 2
// 909.371 us; speedup vs baseline: 3.4593x; 3.4593x over previous
//
#include <hip/hip_runtime.h>
#include <hip/hip_bf16.h>
#include <math.h>

#define DIM 128
#define TOPK 128
#define CAP 4096

__device__ __forceinline__ unsigned f2k(float f) {
    unsigned b = __float_as_uint(f);
    return (b & 0x80000000u) ? ~b : (b | 0x80000000u);
}

__global__ void k_pnorm(const float* __restrict__ p, float* __restrict__ pinv) {
    __shared__ float s[DIM];
    int t = threadIdx.x;
    float v = p[t];
    s[t] = v * v;
    __syncthreads();
    for (int off = 64; off > 0; off >>= 1) {
        if (t < off) s[t] += s[t + off];
        __syncthreads();
    }
    if (t == 0) pinv[0] = 1.0f / sqrtf(s[0]);
}

// wave (64 lanes) per node, float2 per lane
__global__ void k_score(const float* __restrict__ x, const float* __restrict__ p,
                        const float* __restrict__ pinv, float* __restrict__ score, int n) {
    int lane = threadIdx.x & 63;
    int node = blockIdx.x * 4 + (threadIdx.x >> 6);
    if (node >= n) return;
    const float2* x2 = (const float2*)(x) + (size_t)node * 64;
    const float2* p2 = (const float2*)p;
    float2 a = x2[lane], b = p2[lane];
    float acc = a.x * b.x + a.y * b.y;
#pragma unroll
    for (int m = 32; m >= 1; m >>= 1) acc += __shfl_xor(acc, m, 64);
    if (lane == 0) score[node] = acc * pinv[0];
}

__global__ void k_zero(unsigned* __restrict__ hist, unsigned* __restrict__ counter) {
    int i = blockIdx.x * blockDim.x + threadIdx.x;
    if (i < 65536) hist[i] = 0u;
    if (i == 0) counter[0] = 0u;
}

__global__ void k_hist(const float* __restrict__ score, unsigned* __restrict__ hist, int n) {
    int i = blockIdx.x * blockDim.x + threadIdx.x;
    if (i < n) atomicAdd(&hist[f2k(score[i]) >> 16], 1u);
}

// find bin b* with cnt_above(b*) < k <= cnt_above(b*) + hist[b*]
__global__ void k_findbin(const unsigned* __restrict__ hist, unsigned* __restrict__ binfo, int k) {
    __shared__ unsigned csum[1024];
    int t = threadIdx.x;
    unsigned s = 0;
    for (int j = 0; j < 64; ++j) s += hist[t * 64 + j];
    csum[t] = s;
    __syncthreads();
    for (int off = 1; off < 1024; off <<= 1) {
        unsigned v = (t + off < 1024) ? csum[t + off] : 0u;
        __syncthreads();
        csum[t] += v;
        __syncthreads();
    }
    unsigned run = (t + 1 < 1024) ? csum[t + 1] : 0u;   // count in bins > t*64+63
    for (int j = 63; j >= 0; --j) {
        unsigned h = hist[t * 64 + j];
        if (h > 0u && run < (unsigned)k && run + h >= (unsigned)k) {
            binfo[0] = (unsigned)(t * 64 + j);
            binfo[1] = run;
        }
        run += h;
    }
}

__global__ void k_collect(const float* __restrict__ score, const unsigned* __restrict__ binfo,
                          unsigned* __restrict__ counter, float* __restrict__ cval,
                          int* __restrict__ cidx, int n) {
    int i = blockIdx.x * blockDim.x + threadIdx.x;
    if (i >= n) return;
    float s = score[i];
    if ((f2k(s) >> 16) >= binfo[0]) {
        unsigned pos = atomicAdd(counter, 1u);
        if (pos < CAP) { cval[pos] = s; cidx[pos] = i; }
    }
}

// exact top-k, sorted desc, ties -> lower index (matches jax.lax.top_k)
__global__ void k_select(const float* __restrict__ cval, const int* __restrict__ cidx,
                         const unsigned* __restrict__ counter, int* __restrict__ perm,
                         float* __restrict__ vals, int k) {
    __shared__ float sv[CAP];
    __shared__ int si[CAP];
    __shared__ float rv[256];
    __shared__ int ri[256];
    __shared__ int rp[256];
    int t = threadIdx.x;
    unsigned cnt = counter[0];
    int m = (cnt < (unsigned)CAP) ? (int)cnt : CAP;
    for (int i = t; i < m; i += 256) { sv[i] = cval[i]; si[i] = cidx[i]; }
    __syncthreads();
    for (int kk = 0; kk < k; ++kk) {
        float bv = -INFINITY; int bi = 0x7fffffff; int bp = -1;
        for (int i = t; i < m; i += 256) {
            float v = sv[i]; int id = si[i];
            if (v > bv || (v == bv && id < bi)) { bv = v; bi = id; bp = i; }
        }
        rv[t] = bv; ri[t] = bi; rp[t] = bp;
        __syncthreads();
        for (int off = 128; off > 0; off >>= 1) {
            if (t < off) {
                float v2 = rv[t + off]; int i2 = ri[t + off];
                if (v2 > rv[t] || (v2 == rv[t] && i2 < ri[t])) {
                    rv[t] = v2; ri[t] = i2; rp[t] = rp[t + off];
                }
            }
            __syncthreads();
        }
        if (t == 0) {
            perm[kk] = ri[0];
            vals[kk] = rv[0];
            if (rp[0] >= 0) sv[rp[0]] = -INFINITY;
        }
        __syncthreads();
    }
}

__global__ void k_xtilde(const float* __restrict__ x, const int* __restrict__ perm,
                         const float* __restrict__ vals, float* __restrict__ xt) {
    int i = blockIdx.x, c = threadIdx.x;
    xt[i * DIM + c] = x[(size_t)perm[i] * DIM + c] * tanhf(vals[i]);
}

__global__ void k_gru(const float* __restrict__ xt, const float* __restrict__ W0,
                      const float* __restrict__ w_ih, const float* __restrict__ w_hh,
                      const float* __restrict__ b_ih, const float* __restrict__ b_hh,
                      float* __restrict__ W) {
    __shared__ float sx[DIM], sh[DIM];
    int i = blockIdx.x, c = threadIdx.x;
    sx[c] = xt[i * DIM + c];
    sh[c] = W0[i * DIM + c];
    __syncthreads();
    float gr = b_ih[c], gz = b_ih[DIM + c], gn = b_ih[2 * DIM + c];
    float hr = b_hh[c], hz = b_hh[DIM + c], hn = b_hh[2 * DIM + c];
    const float* wr = w_ih + (size_t)c * DIM;
    const float* wz = w_ih + (size_t)(DIM + c) * DIM;
    const float* wn = w_ih + (size_t)(2 * DIM + c) * DIM;
    const float* ur = w_hh + (size_t)c * DIM;
    const float* uz = w_hh + (size_t)(DIM + c) * DIM;
    const float* un = w_hh + (size_t)(2 * DIM + c) * DIM;
    for (int d = 0; d < DIM; ++d) {
        float xd = sx[d], hd = sh[d];
        gr += xd * wr[d]; gz += xd * wz[d]; gn += xd * wn[d];
        hr += hd * ur[d]; hz += hd * uz[d]; hn += hd * un[d];
    }
    float r = 1.0f / (1.0f + expf(-(gr + hr)));
    float z = 1.0f / (1.0f + expf(-(gz + hz)));
    float nn = tanhf(gn + r * hn);
    W[i * DIM + c] = (1.0f - z) * nn + z * sh[c];
}

// wdeg <- 1.0 (self loop), cnt <- 0
__global__ void k_deg_init(float* __restrict__ wdeg, int* __restrict__ cnt, int n) {
    int i = blockIdx.x * blockDim.x + threadIdx.x;
    if (i < n) { wdeg[i] = 1.0f; cnt[i] = 0; }
}

// weighted degree (for norm) + integer in-degree (for CSR offsets)
__global__ void k_deg_cnt(const int* __restrict__ ei, const float* __restrict__ ew,
                          float* __restrict__ wdeg, int* __restrict__ cnt, int ne) {
    int e = blockIdx.x * blockDim.x + threadIdx.x;
    if (e < ne) {
        int c = ei[ne + e];
        atomicAdd(&wdeg[c], ew[e]);
        atomicAdd(&cnt[c], 1);
    }
}

__global__ void k_dinv(float* __restrict__ deg, int n) {
    int i = blockIdx.x * blockDim.x + threadIdx.x;
    if (i < n) {
        float v = deg[i];
        deg[i] = (v > 0.0f) ? (1.0f / sqrtf(v)) : 0.0f;
    }
}

// one-block exclusive scan of cnt[0..n) -> offs[0..n], cursor copy
__global__ void k_scan(const int* __restrict__ cnt, int* __restrict__ offs,
                       int* __restrict__ cursor, int n) {
    __shared__ int part[1024];
    int t = threadIdx.x;
    int chunk = (n + 1023) >> 10;
    int lo = t * chunk;
    int hi = lo + chunk; if (hi > n) hi = n;
    int s = 0;
    for (int i = lo; i < hi; ++i) s += cnt[i];
    part[t] = s;
    __syncthreads();
    for (int off = 1; off < 1024; off <<= 1) {
        int v = (t >= off) ? part[t - off] : 0;
        __syncthreads();
        part[t] += v;
        __syncthreads();
    }
    int run = (t > 0) ? part[t - 1] : 0;   // exclusive base for this chunk
    for (int i = lo; i < hi; ++i) {
        offs[i] = run; cursor[i] = run; run += cnt[i];
    }
    if (t == 1023) offs[n] = part[1023];
}

// bucket edges by destination: edata[pos] = {src, norm}
__global__ void k_fill(const int* __restrict__ ei, const float* __restrict__ ew,
                       const float* __restrict__ dinv, int* __restrict__ cursor,
                       int2* __restrict__ edata, int ne) {
    int e = blockIdx.x * blockDim.x + threadIdx.x;
    if (e >= ne) return;
    int r = ei[e], c = ei[ne + e];
    float nrm = dinv[r] * ew[e] * dinv[c];
    int pos = atomicAdd(&cursor[c], 1);
    edata[pos] = make_int2(r, __float_as_int(nrm));
}

// xw = x @ W ; 64x64 block tile, 4x4 per thread, x stored transposed [k][r] in LDS
__global__ __launch_bounds__(256) void k_xw(const float* __restrict__ x,
                                            const float* __restrict__ W,
                                            float* __restrict__ xw, int n) {
    __shared__ float xsT[DIM * 64];  // [k][r]  32KB
    __shared__ float wls[DIM * 64];  // [k][c]  32KB
    int t = threadIdx.x;
    int r0 = blockIdx.x * 64;
    int c0 = blockIdx.y * 64;
    const float4* W4 = (const float4*)W;
#pragma unroll
    for (int it = 0; it < 8; ++it) {
        int id = t + it * 256;
        int k = id >> 4, c4 = id & 15;
        float4 w = W4[k * 32 + (c0 >> 2) + c4];
        *((float4*)&wls[k * 64 + c4 * 4]) = w;
    }
#pragma unroll
    for (int it = 0; it < 8; ++it) {
        int id = t + it * 256;
        int r = id & 63, k4 = id >> 6;
        int row = r0 + r; if (row >= n) row = n - 1;
        float4 v = *((const float4*)&x[(size_t)row * DIM + k4 * 4]);
        xsT[(k4 * 4 + 0) * 64 + r] = v.x;
        xsT[(k4 * 4 + 1) * 64 + r] = v.y;
        xsT[(k4 * 4 + 2) * 64 + r] = v.z;
        xsT[(k4 * 4 + 3) * 64 + r] = v.w;
    }
    __syncthreads();
    int tc = t & 15, tr = t >> 4;
    float acc[4][4];
#pragma unroll
    for (int i = 0; i < 4; ++i)
#pragma unroll
        for (int j = 0; j < 4; ++j) acc[i][j] = 0.0f;
#pragma unroll 4
    for (int k = 0; k < DIM; ++k) {
        float4 xa = *((const float4*)&xsT[k * 64 + tr * 4]);
        float4 wa = *((const float4*)&wls[k * 64 + tc * 4]);
        float xv[4] = {xa.x, xa.y, xa.z, xa.w};
        float wv[4] = {wa.x, wa.y, wa.z, wa.w};
#pragma unroll
        for (int i = 0; i < 4; ++i)
#pragma unroll
            for (int j = 0; j < 4; ++j) acc[i][j] += xv[i] * wv[j];
    }
#pragma unroll
    for (int i = 0; i < 4; ++i) {
        int row = r0 + tr * 4 + i;
        if (row < n) {
            float4 o = {acc[i][0], acc[i][1], acc[i][2], acc[i][3]};
            *((float4*)&xw[(size_t)row * DIM + c0 + tc * 4]) = o;
        }
    }
}

// per-node gather + fused relu-linear head: 32 lanes per node, float4 each
__global__ __launch_bounds__(256) void k_gather(const float* __restrict__ xw,
        const float* __restrict__ dinv, const int* __restrict__ offs,
        const int2* __restrict__ edata, const float* __restrict__ w_lin,
        const float* __restrict__ b_lin, float* __restrict__ out, int n) {
    int gid = blockIdx.x * 256 + threadIdx.x;
    int c = gid >> 5, lane = gid & 31;
    if (c >= n) return;
    const float4* xw4 = (const float4*)xw;
    float dd = dinv[c]; dd *= dd;                      // self-loop norm
    float4 a = xw4[(size_t)c * 32 + lane];
    float4 acc = {a.x * dd, a.y * dd, a.z * dd, a.w * dd};
    int start = offs[c], end = offs[c + 1];
    for (int base = start; base < end; base += 32) {
        int m = end - base; if (m > 32) m = 32;
        int2 ed = (base + lane < end) ? edata[base + lane] : make_int2(0, 0);
        for (int j0 = 0; j0 < m; j0 += 4) {
#pragma unroll
            for (int jj = 0; jj < 4; ++jj) {
                int j = j0 + jj;
                int src = __shfl(ed.x, j, 32);
                float nrm = (j < m) ? __int_as_float(__shfl(ed.y, j, 32)) : 0.0f;
                float4 v = xw4[(size_t)src * 32 + lane];
                acc.x += v.x * nrm; acc.y += v.y * nrm;
                acc.z += v.z * nrm; acc.w += v.w * nrm;
            }
        }
    }
    float4 wl = ((const float4*)w_lin)[lane];
    float r = fmaxf(acc.x, 0.0f) * wl.x + fmaxf(acc.y, 0.0f) * wl.y +
              fmaxf(acc.z, 0.0f) * wl.z + fmaxf(acc.w, 0.0f) * wl.w;
#pragma unroll
    for (int m = 16; m >= 1; m >>= 1) r += __shfl_xor(r, m, 32);
    if (lane == 0) out[c] = r + b_lin[0];
}

extern "C" void kernel_launch(void* const* d_in, const int* in_sizes, int n_in,
                              void* d_out, int out_size, void* d_ws, size_t ws_size,
                              hipStream_t stream) {
    const float* x     = (const float*)d_in[0];
    const int*   ei    = (const int*)d_in[1];
    const float* ew    = (const float*)d_in[2];
    const float* p     = (const float*)d_in[3];
    const float* W0    = (const float*)d_in[4];
    const float* w_ih  = (const float*)d_in[5];
    const float* w_hh  = (const float*)d_in[6];
    const float* b_ih  = (const float*)d_in[7];
    const float* b_hh  = (const float*)d_in[8];
    const float* w_lin = (const float*)d_in[9];
    const float* b_lin = (const float*)d_in[10];
    float* out = (float*)d_out;
    int n  = in_sizes[0] / DIM;
    int ne = in_sizes[2];
    (void)n_in; (void)out_size; (void)ws_size;

    char* base = (char*)d_ws;
    size_t o = 0;
    auto alloc = [&](size_t b) { size_t r = o; o += (b + 255) & ~(size_t)255; return r; };
    float*    score   = (float*)(base + alloc((size_t)n * 4));
    unsigned* hist    = (unsigned*)(base + alloc(65536 * 4));
    unsigned* counter = (unsigned*)(base + alloc(256));
    unsigned* binfo   = (unsigned*)(base + alloc(256));
    float*    cval    = (float*)(base + alloc((size_t)CAP * 4));
    int*      cidx    = (int*)(base + alloc((size_t)CAP * 4));
    int*      perm    = (int*)(base + alloc(TOPK * 4));
    float*    vals    = (float*)(base + alloc(TOPK * 4));
    float*    pinv    = (float*)(base + alloc(256));
    float*    xt      = (float*)(base + alloc(DIM * DIM * 4));
    float*    Wm      = (float*)(base + alloc(DIM * DIM * 4));
    float*    dinv    = (float*)(base + alloc((size_t)n * 4));
    int*      cnt     = (int*)(base + alloc((size_t)n * 4));
    int*      offs    = (int*)(base + alloc((size_t)(n + 1) * 4));
    int*      cursor  = (int*)(base + alloc((size_t)n * 4));
    int2*     edata   = (int2*)(base + alloc((size_t)ne * 8));
    float*    xw      = (float*)(base + alloc((size_t)n * DIM * 4));

    k_pnorm<<<1, DIM, 0, stream>>>(p, pinv);
    k_score<<<(n + 3) / 4, 256, 0, stream>>>(x, p, pinv, score, n);
    k_zero<<<(65537 + 255) / 256, 256, 0, stream>>>(hist, counter);
    k_hist<<<(n + 255) / 256, 256, 0, stream>>>(score, hist, n);
    k_findbin<<<1, 1024, 0, stream>>>(hist, binfo, TOPK);
    k_collect<<<(n + 255) / 256, 256, 0, stream>>>(score, binfo, counter, cval, cidx, n);
    k_select<<<1, 256, 0, stream>>>(cval, cidx, counter, perm, vals, TOPK);
    k_xtilde<<<DIM, DIM, 0, stream>>>(x, perm, vals, xt);
    k_gru<<<DIM, DIM, 0, stream>>>(xt, W0, w_ih, w_hh, b_ih, b_hh, Wm);
    k_deg_init<<<(n + 255) / 256, 256, 0, stream>>>(dinv, cnt, n);
    k_deg_cnt<<<(ne + 255) / 256, 256, 0, stream>>>(ei, ew, dinv, cnt, ne);
    k_dinv<<<(n + 255) / 256, 256, 0, stream>>>(dinv, n);
    k_scan<<<1, 1024, 0, stream>>>(cnt, offs, cursor, n);
    k_fill<<<(ne + 255) / 256, 256, 0, stream>>>(ei, ew, dinv, cursor, edata, ne);
    dim3 gxw((n + 63) / 64, 2);
    k_xw<<<gxw, 256, 0, stream>>>(x, Wm, xw, n);
    long long g_threads = (long long)n * 32;
    k_gather<<<(int)((g_threads + 255) / 256), 256, 0, stream>>>(
        xw, dinv, offs, edata, w_lin, b_lin, out, n);
}

// Round 3
// 688.962 us; speedup vs baseline: 4.5660x; 1.3199x over previous
//
#include <hip/hip_runtime.h>
#include <hip/hip_bf16.h>
#include <math.h>

#define DIM 128
#define TOPK 128
#define CAP 4096
#define SCAN_B 256

__device__ __forceinline__ unsigned f2k(float f) {
    unsigned b = __float_as_uint(f);
    return (b & 0x80000000u) ? ~b : (b | 0x80000000u);
}

__global__ void k_pnorm(const float* __restrict__ p, float* __restrict__ pinv) {
    __shared__ float s[DIM];
    int t = threadIdx.x;
    float v = p[t];
    s[t] = v * v;
    __syncthreads();
    for (int off = 64; off > 0; off >>= 1) {
        if (t < off) s[t] += s[t + off];
        __syncthreads();
    }
    if (t == 0) pinv[0] = 1.0f / sqrtf(s[0]);
}

// wave (64 lanes) per node, float2 per lane
__global__ void k_score(const float* __restrict__ x, const float* __restrict__ p,
                        const float* __restrict__ pinv, float* __restrict__ score, int n) {
    int lane = threadIdx.x & 63;
    int node = blockIdx.x * 4 + (threadIdx.x >> 6);
    if (node >= n) return;
    const float2* x2 = (const float2*)(x) + (size_t)node * 64;
    const float2* p2 = (const float2*)p;
    float2 a = x2[lane], b = p2[lane];
    float acc = a.x * b.x + a.y * b.y;
#pragma unroll
    for (int m = 32; m >= 1; m >>= 1) acc += __shfl_xor(acc, m, 64);
    if (lane == 0) score[node] = acc * pinv[0];
}

__global__ void k_zero(unsigned* __restrict__ hist, unsigned* __restrict__ counter) {
    int i = blockIdx.x * blockDim.x + threadIdx.x;
    if (i < 65536) hist[i] = 0u;
    if (i == 0) counter[0] = 0u;
}

__global__ void k_hist(const float* __restrict__ score, unsigned* __restrict__ hist, int n) {
    int i = blockIdx.x * blockDim.x + threadIdx.x;
    if (i < n) atomicAdd(&hist[f2k(score[i]) >> 16], 1u);
}

// find bin b* with cnt_above(b*) < k <= cnt_above(b*) + hist[b*]
__global__ void k_findbin(const unsigned* __restrict__ hist, unsigned* __restrict__ binfo, int k) {
    __shared__ unsigned csum[1024];
    int t = threadIdx.x;
    unsigned s = 0;
    for (int j = 0; j < 64; ++j) s += hist[t * 64 + j];
    csum[t] = s;
    __syncthreads();
    for (int off = 1; off < 1024; off <<= 1) {
        unsigned v = (t + off < 1024) ? csum[t + off] : 0u;
        __syncthreads();
        csum[t] += v;
        __syncthreads();
    }
    unsigned run = (t + 1 < 1024) ? csum[t + 1] : 0u;   // count in bins > t*64+63
    for (int j = 63; j >= 0; --j) {
        unsigned h = hist[t * 64 + j];
        if (h > 0u && run < (unsigned)k && run + h >= (unsigned)k) {
            binfo[0] = (unsigned)(t * 64 + j);
            binfo[1] = run;
        }
        run += h;
    }
}

__global__ void k_collect(const float* __restrict__ score, const unsigned* __restrict__ binfo,
                          unsigned* __restrict__ counter, float* __restrict__ cval,
                          int* __restrict__ cidx, int n) {
    int i = blockIdx.x * blockDim.x + threadIdx.x;
    if (i >= n) return;
    float s = score[i];
    if ((f2k(s) >> 16) >= binfo[0]) {
        unsigned pos = atomicAdd(counter, 1u);
        if (pos < CAP) { cval[pos] = s; cidx[pos] = i; }
    }
}

// exact top-k, sorted desc, ties -> lower index (matches jax.lax.top_k)
__global__ void k_select(const float* __restrict__ cval, const int* __restrict__ cidx,
                         const unsigned* __restrict__ counter, int* __restrict__ perm,
                         float* __restrict__ vals, int k) {
    __shared__ float sv[CAP];
    __shared__ int si[CAP];
    __shared__ float rv[256];
    __shared__ int ri[256];
    __shared__ int rp[256];
    int t = threadIdx.x;
    unsigned cnt = counter[0];
    int m = (cnt < (unsigned)CAP) ? (int)cnt : CAP;
    for (int i = t; i < m; i += 256) { sv[i] = cval[i]; si[i] = cidx[i]; }
    __syncthreads();
    for (int kk = 0; kk < k; ++kk) {
        float bv = -INFINITY; int bi = 0x7fffffff; int bp = -1;
        for (int i = t; i < m; i += 256) {
            float v = sv[i]; int id = si[i];
            if (v > bv || (v == bv && id < bi)) { bv = v; bi = id; bp = i; }
        }
        rv[t] = bv; ri[t] = bi; rp[t] = bp;
        __syncthreads();
        for (int off = 128; off > 0; off >>= 1) {
            if (t < off) {
                float v2 = rv[t + off]; int i2 = ri[t + off];
                if (v2 > rv[t] || (v2 == rv[t] && i2 < ri[t])) {
                    rv[t] = v2; ri[t] = i2; rp[t] = rp[t + off];
                }
            }
            __syncthreads();
        }
        if (t == 0) {
            perm[kk] = ri[0];
            vals[kk] = rv[0];
            if (rp[0] >= 0) sv[rp[0]] = -INFINITY;
        }
        __syncthreads();
    }
}

__global__ void k_xtilde(const float* __restrict__ x, const int* __restrict__ perm,
                         const float* __restrict__ vals, float* __restrict__ xt) {
    int i = blockIdx.x, c = threadIdx.x;
    xt[i * DIM + c] = x[(size_t)perm[i] * DIM + c] * tanhf(vals[i]);
}

__global__ void k_gru(const float* __restrict__ xt, const float* __restrict__ W0,
                      const float* __restrict__ w_ih, const float* __restrict__ w_hh,
                      const float* __restrict__ b_ih, const float* __restrict__ b_hh,
                      float* __restrict__ W) {
    __shared__ float sx[DIM], sh[DIM];
    int i = blockIdx.x, c = threadIdx.x;
    sx[c] = xt[i * DIM + c];
    sh[c] = W0[i * DIM + c];
    __syncthreads();
    float gr = b_ih[c], gz = b_ih[DIM + c], gn = b_ih[2 * DIM + c];
    float hr = b_hh[c], hz = b_hh[DIM + c], hn = b_hh[2 * DIM + c];
    const float* wr = w_ih + (size_t)c * DIM;
    const float* wz = w_ih + (size_t)(DIM + c) * DIM;
    const float* wn = w_ih + (size_t)(2 * DIM + c) * DIM;
    const float* ur = w_hh + (size_t)c * DIM;
    const float* uz = w_hh + (size_t)(DIM + c) * DIM;
    const float* un = w_hh + (size_t)(2 * DIM + c) * DIM;
    for (int d = 0; d < DIM; ++d) {
        float xd = sx[d], hd = sh[d];
        gr += xd * wr[d]; gz += xd * wz[d]; gn += xd * wn[d];
        hr += hd * ur[d]; hz += hd * uz[d]; hn += hd * un[d];
    }
    float r = 1.0f / (1.0f + expf(-(gr + hr)));
    float z = 1.0f / (1.0f + expf(-(gz + hz)));
    float nn = tanhf(gn + r * hn);
    W[i * DIM + c] = (1.0f - z) * nn + z * sh[c];
}

// wdeg <- 1.0 (self loop), cnt <- 0
__global__ void k_deg_init(float* __restrict__ wdeg, int* __restrict__ cnt, int n) {
    int i = blockIdx.x * blockDim.x + threadIdx.x;
    if (i < n) { wdeg[i] = 1.0f; cnt[i] = 0; }
}

// weighted degree (for norm) + integer in-degree (for CSR offsets)
__global__ void k_deg_cnt(const int* __restrict__ ei, const float* __restrict__ ew,
                          float* __restrict__ wdeg, int* __restrict__ cnt, int ne) {
    int e = blockIdx.x * blockDim.x + threadIdx.x;
    if (e < ne) {
        int c = ei[ne + e];
        atomicAdd(&wdeg[c], ew[e]);
        atomicAdd(&cnt[c], 1);
    }
}

__global__ void k_dinv(float* __restrict__ deg, int n) {
    int i = blockIdx.x * blockDim.x + threadIdx.x;
    if (i < n) {
        float v = deg[i];
        deg[i] = (v > 0.0f) ? (1.0f / sqrtf(v)) : 0.0f;
    }
}

// ---- 3-phase multi-block exclusive scan of cnt -> offs/cursor ----
__global__ void k_scan1(const int* __restrict__ cnt, int* __restrict__ bsum, int n) {
    __shared__ int red[256];
    int b = blockIdx.x, t = threadIdx.x;
    int chunk = (n + SCAN_B - 1) / SCAN_B;
    int lo = b * chunk;
    int hi = lo + chunk; if (hi > n) hi = n;
    int s = 0;
    for (int i = lo + t; i < hi; i += 256) s += cnt[i];
    red[t] = s;
    __syncthreads();
    for (int off = 128; off > 0; off >>= 1) {
        if (t < off) red[t] += red[t + off];
        __syncthreads();
    }
    if (t == 0) bsum[b] = red[0];
}

__global__ void k_scan2(const int* __restrict__ bsum, int* __restrict__ bbase) {
    __shared__ int s[SCAN_B];
    int t = threadIdx.x;
    s[t] = bsum[t];
    __syncthreads();
    for (int off = 1; off < SCAN_B; off <<= 1) {
        int v = (t >= off) ? s[t - off] : 0;
        __syncthreads();
        s[t] += v;
        __syncthreads();
    }
    bbase[t] = (t > 0) ? s[t - 1] : 0;   // exclusive
    if (t == SCAN_B - 1) bbase[SCAN_B] = s[SCAN_B - 1];  // total
}

__global__ void k_scan3(const int* __restrict__ cnt, const int* __restrict__ bbase,
                        int* __restrict__ offs, int* __restrict__ cursor, int n) {
    __shared__ int red[256];
    int b = blockIdx.x, t = threadIdx.x;
    int chunk = (n + SCAN_B - 1) / SCAN_B;
    int lo = b * chunk;
    int hi = lo + chunk; if (hi > n) hi = n;
    int tchunk = (chunk + 255) / 256;
    int tlo = lo + t * tchunk;
    int thi = tlo + tchunk; if (thi > hi) thi = hi;
    int s = 0;
    for (int i = tlo; i < thi; ++i) s += cnt[i];
    red[t] = s;
    __syncthreads();
    for (int off = 1; off < 256; off <<= 1) {
        int v = (t >= off) ? red[t - off] : 0;
        __syncthreads();
        red[t] += v;
        __syncthreads();
    }
    int run = bbase[b] + ((t > 0) ? red[t - 1] : 0);
    for (int i = tlo; i < thi; ++i) {
        offs[i] = run; cursor[i] = run; run += cnt[i];
    }
    if (b == 0 && t == 0) offs[n] = bbase[SCAN_B];
}

// bucket edges by destination: edata[pos] = {src, norm}
__global__ void k_fill(const int* __restrict__ ei, const float* __restrict__ ew,
                       const float* __restrict__ dinv, int* __restrict__ cursor,
                       int2* __restrict__ edata, int ne) {
    int e = blockIdx.x * blockDim.x + threadIdx.x;
    if (e >= ne) return;
    int r = ei[e], c = ei[ne + e];
    float nrm = dinv[r] * ew[e] * dinv[c];
    int pos = atomicAdd(&cursor[c], 1);
    edata[pos] = make_int2(r, __float_as_int(nrm));
}

// xw = x @ W ; 64x64 block tile, 4x4 per thread, x stored transposed [k][r] in LDS
__global__ __launch_bounds__(256) void k_xw(const float* __restrict__ x,
                                            const float* __restrict__ W,
                                            float* __restrict__ xw, int n) {
    __shared__ float xsT[DIM * 64];  // [k][r]  32KB
    __shared__ float wls[DIM * 64];  // [k][c]  32KB
    int t = threadIdx.x;
    int r0 = blockIdx.x * 64;
    int c0 = blockIdx.y * 64;
    const float4* W4 = (const float4*)W;
#pragma unroll
    for (int it = 0; it < 8; ++it) {
        int id = t + it * 256;
        int k = id >> 4, c4 = id & 15;
        float4 w = W4[k * 32 + (c0 >> 2) + c4];
        *((float4*)&wls[k * 64 + c4 * 4]) = w;
    }
#pragma unroll
    for (int it = 0; it < 8; ++it) {
        int id = t + it * 256;
        int r = id & 63, k4 = id >> 6;
        int row = r0 + r; if (row >= n) row = n - 1;
        float4 v = *((const float4*)&x[(size_t)row * DIM + k4 * 4]);
        xsT[(k4 * 4 + 0) * 64 + r] = v.x;
        xsT[(k4 * 4 + 1) * 64 + r] = v.y;
        xsT[(k4 * 4 + 2) * 64 + r] = v.z;
        xsT[(k4 * 4 + 3) * 64 + r] = v.w;
    }
    __syncthreads();
    int tc = t & 15, tr = t >> 4;
    float acc[4][4];
#pragma unroll
    for (int i = 0; i < 4; ++i)
#pragma unroll
        for (int j = 0; j < 4; ++j) acc[i][j] = 0.0f;
#pragma unroll 4
    for (int k = 0; k < DIM; ++k) {
        float4 xa = *((const float4*)&xsT[k * 64 + tr * 4]);
        float4 wa = *((const float4*)&wls[k * 64 + tc * 4]);
        float xv[4] = {xa.x, xa.y, xa.z, xa.w};
        float wv[4] = {wa.x, wa.y, wa.z, wa.w};
#pragma unroll
        for (int i = 0; i < 4; ++i)
#pragma unroll
            for (int j = 0; j < 4; ++j) acc[i][j] += xv[i] * wv[j];
    }
#pragma unroll
    for (int i = 0; i < 4; ++i) {
        int row = r0 + tr * 4 + i;
        if (row < n) {
            float4 o = {acc[i][0], acc[i][1], acc[i][2], acc[i][3]};
            *((float4*)&xw[(size_t)row * DIM + c0 + tc * 4]) = o;
        }
    }
}

// per-node gather + fused relu-linear head: 32 lanes per node, float4 each
__global__ __launch_bounds__(256) void k_gather(const float* __restrict__ xw,
        const float* __restrict__ dinv, const int* __restrict__ offs,
        const int2* __restrict__ edata, const float* __restrict__ w_lin,
        const float* __restrict__ b_lin, float* __restrict__ out, int n) {
    int gid = blockIdx.x * 256 + threadIdx.x;
    int c = gid >> 5, lane = gid & 31;
    if (c >= n) return;
    const float4* xw4 = (const float4*)xw;
    float dd = dinv[c]; dd *= dd;                      // self-loop norm
    float4 a = xw4[(size_t)c * 32 + lane];
    float4 acc = {a.x * dd, a.y * dd, a.z * dd, a.w * dd};
    int start = offs[c], end = offs[c + 1];
    for (int base = start; base < end; base += 32) {
        int m = end - base; if (m > 32) m = 32;
        int2 ed = (base + lane < end) ? edata[base + lane] : make_int2(0, 0);
        for (int j0 = 0; j0 < m; j0 += 4) {
#pragma unroll
            for (int jj = 0; jj < 4; ++jj) {
                int j = j0 + jj;
                int src = __shfl(ed.x, j, 32);
                float nrm = (j < m) ? __int_as_float(__shfl(ed.y, j, 32)) : 0.0f;
                float4 v = xw4[(size_t)src * 32 + lane];
                acc.x += v.x * nrm; acc.y += v.y * nrm;
                acc.z += v.z * nrm; acc.w += v.w * nrm;
            }
        }
    }
    float4 wl = ((const float4*)w_lin)[lane];
    float r = fmaxf(acc.x, 0.0f) * wl.x + fmaxf(acc.y, 0.0f) * wl.y +
              fmaxf(acc.z, 0.0f) * wl.z + fmaxf(acc.w, 0.0f) * wl.w;
#pragma unroll
    for (int m = 16; m >= 1; m >>= 1) r += __shfl_xor(r, m, 32);
    if (lane == 0) out[c] = r + b_lin[0];
}

extern "C" void kernel_launch(void* const* d_in, const int* in_sizes, int n_in,
                              void* d_out, int out_size, void* d_ws, size_t ws_size,
                              hipStream_t stream) {
    const float* x     = (const float*)d_in[0];
    const int*   ei    = (const int*)d_in[1];
    const float* ew    = (const float*)d_in[2];
    const float* p     = (const float*)d_in[3];
    const float* W0    = (const float*)d_in[4];
    const float* w_ih  = (const float*)d_in[5];
    const float* w_hh  = (const float*)d_in[6];
    const float* b_ih  = (const float*)d_in[7];
    const float* b_hh  = (const float*)d_in[8];
    const float* w_lin = (const float*)d_in[9];
    const float* b_lin = (const float*)d_in[10];
    float* out = (float*)d_out;
    int n  = in_sizes[0] / DIM;
    int ne = in_sizes[2];
    (void)n_in; (void)out_size; (void)ws_size;

    char* base = (char*)d_ws;
    size_t o = 0;
    auto alloc = [&](size_t b) { size_t r = o; o += (b + 255) & ~(size_t)255; return r; };
    float*    score   = (float*)(base + alloc((size_t)n * 4));
    unsigned* hist    = (unsigned*)(base + alloc(65536 * 4));
    unsigned* counter = (unsigned*)(base + alloc(256));
    unsigned* binfo   = (unsigned*)(base + alloc(256));
    float*    cval    = (float*)(base + alloc((size_t)CAP * 4));
    int*      cidx    = (int*)(base + alloc((size_t)CAP * 4));
    int*      perm    = (int*)(base + alloc(TOPK * 4));
    float*    vals    = (float*)(base + alloc(TOPK * 4));
    float*    pinv    = (float*)(base + alloc(256));
    float*    xt      = (float*)(base + alloc(DIM * DIM * 4));
    float*    Wm      = (float*)(base + alloc(DIM * DIM * 4));
    float*    dinv    = (float*)(base + alloc((size_t)n * 4));
    int*      cnt     = (int*)(base + alloc((size_t)n * 4));
    int*      offs    = (int*)(base + alloc((size_t)(n + 1) * 4));
    int*      cursor  = (int*)(base + alloc((size_t)n * 4));
    int*      bsum    = (int*)(base + alloc((SCAN_B + 1) * 4));
    int*      bbase   = (int*)(base + alloc((SCAN_B + 1) * 4));
    int2*     edata   = (int2*)(base + alloc((size_t)ne * 8));
    float*    xw      = (float*)(base + alloc((size_t)n * DIM * 4));

    k_pnorm<<<1, DIM, 0, stream>>>(p, pinv);
    k_score<<<(n + 3) / 4, 256, 0, stream>>>(x, p, pinv, score, n);
    k_zero<<<(65537 + 255) / 256, 256, 0, stream>>>(hist, counter);
    k_hist<<<(n + 255) / 256, 256, 0, stream>>>(score, hist, n);
    k_findbin<<<1, 1024, 0, stream>>>(hist, binfo, TOPK);
    k_collect<<<(n + 255) / 256, 256, 0, stream>>>(score, binfo, counter, cval, cidx, n);
    k_select<<<1, 256, 0, stream>>>(cval, cidx, counter, perm, vals, TOPK);
    k_xtilde<<<DIM, DIM, 0, stream>>>(x, perm, vals, xt);
    k_gru<<<DIM, DIM, 0, stream>>>(xt, W0, w_ih, w_hh, b_ih, b_hh, Wm);
    k_deg_init<<<(n + 255) / 256, 256, 0, stream>>>(dinv, cnt, n);
    k_deg_cnt<<<(ne + 255) / 256, 256, 0, stream>>>(ei, ew, dinv, cnt, ne);
    k_dinv<<<(n + 255) / 256, 256, 0, stream>>>(dinv, n);
    k_scan1<<<SCAN_B, 256, 0, stream>>>(cnt, bsum, n);
    k_scan2<<<1, SCAN_B, 0, stream>>>(bsum, bbase);
    k_scan3<<<SCAN_B, 256, 0, stream>>>(cnt, bbase, offs, cursor, n);
    k_fill<<<(ne + 255) / 256, 256, 0, stream>>>(ei, ew, dinv, cursor, edata, ne);
    dim3 gxw((n + 63) / 64, 2);
    k_xw<<<gxw, 256, 0, stream>>>(x, Wm, xw, n);
    long long g_threads = (long long)n * 32;
    k_gather<<<(int)((g_threads + 255) / 256), 256, 0, stream>>>(
        xw, dinv, offs, edata, w_lin, b_lin, out, n);
}

// Round 4
// 534.558 us; speedup vs baseline: 5.8849x; 1.2888x over previous
//
#include <hip/hip_runtime.h>
#include <hip/hip_bf16.h>
#include <math.h>

#define DIM 128
#define TOPK 128
#define CAP 4096
#define SCAN_B 256

__device__ __forceinline__ unsigned f2k(float f) {
    unsigned b = __float_as_uint(f);
    return (b & 0x80000000u) ? ~b : (b | 0x80000000u);
}

__global__ void k_pnorm(const float* __restrict__ p, float* __restrict__ pinv) {
    __shared__ float s[DIM];
    int t = threadIdx.x;
    float v = p[t];
    s[t] = v * v;
    __syncthreads();
    for (int off = 64; off > 0; off >>= 1) {
        if (t < off) s[t] += s[t + off];
        __syncthreads();
    }
    if (t == 0) pinv[0] = 1.0f / sqrtf(s[0]);
}

// wave (64 lanes) per node, float2 per lane
__global__ void k_score(const float* __restrict__ x, const float* __restrict__ p,
                        const float* __restrict__ pinv, float* __restrict__ score, int n) {
    int lane = threadIdx.x & 63;
    int node = blockIdx.x * 4 + (threadIdx.x >> 6);
    if (node >= n) return;
    const float2* x2 = (const float2*)(x) + (size_t)node * 64;
    const float2* p2 = (const float2*)p;
    float2 a = x2[lane], b = p2[lane];
    float acc = a.x * b.x + a.y * b.y;
#pragma unroll
    for (int m = 32; m >= 1; m >>= 1) acc += __shfl_xor(acc, m, 64);
    if (lane == 0) score[node] = acc * pinv[0];
}

__global__ void k_zero(unsigned* __restrict__ hist, unsigned* __restrict__ counter) {
    int i = blockIdx.x * blockDim.x + threadIdx.x;
    if (i < 65536) hist[i] = 0u;
    if (i == 0) counter[0] = 0u;
}

__global__ void k_hist(const float* __restrict__ score, unsigned* __restrict__ hist, int n) {
    int i = blockIdx.x * blockDim.x + threadIdx.x;
    if (i < n) atomicAdd(&hist[f2k(score[i]) >> 16], 1u);
}

// find bin b* with cnt_above(b*) < k <= cnt_above(b*) + hist[b*]
__global__ void k_findbin(const unsigned* __restrict__ hist, unsigned* __restrict__ binfo, int k) {
    __shared__ unsigned csum[1024];
    int t = threadIdx.x;
    unsigned s = 0;
    for (int j = 0; j < 64; ++j) s += hist[t * 64 + j];
    csum[t] = s;
    __syncthreads();
    for (int off = 1; off < 1024; off <<= 1) {
        unsigned v = (t + off < 1024) ? csum[t + off] : 0u;
        __syncthreads();
        csum[t] += v;
        __syncthreads();
    }
    unsigned run = (t + 1 < 1024) ? csum[t + 1] : 0u;   // count in bins > t*64+63
    for (int j = 63; j >= 0; --j) {
        unsigned h = hist[t * 64 + j];
        if (h > 0u && run < (unsigned)k && run + h >= (unsigned)k) {
            binfo[0] = (unsigned)(t * 64 + j);
            binfo[1] = run;
        }
        run += h;
    }
}

__global__ void k_collect(const float* __restrict__ score, const unsigned* __restrict__ binfo,
                          unsigned* __restrict__ counter, float* __restrict__ cval,
                          int* __restrict__ cidx, int n) {
    int i = blockIdx.x * blockDim.x + threadIdx.x;
    if (i >= n) return;
    float s = score[i];
    if ((f2k(s) >> 16) >= binfo[0]) {
        unsigned pos = atomicAdd(counter, 1u);
        if (pos < CAP) { cval[pos] = s; cidx[pos] = i; }
    }
}

// rank-based exact top-k: rank = #{j : v_j > v_i || (v_j==v_i && id_j < id_i)}
// matches jax.lax.top_k (sorted desc, lower index wins ties). No barriers.
__global__ void k_rank(const float* __restrict__ cval, const int* __restrict__ cidx,
                       const unsigned* __restrict__ counter, int* __restrict__ perm,
                       float* __restrict__ vals, int k) {
    int i = blockIdx.x * blockDim.x + threadIdx.x;
    unsigned cnt = counter[0];
    int m = (cnt < (unsigned)CAP) ? (int)cnt : CAP;
    if (i >= m) return;
    float v = cval[i]; int id = cidx[i];
    int rank = 0;
    for (int j = 0; j < m; ++j) {
        float vj = cval[j]; int ij = cidx[j];
        if (vj > v || (vj == v && ij < id)) ++rank;
    }
    if (rank < k) { perm[rank] = id; vals[rank] = v; }
}

__global__ void k_xtilde(const float* __restrict__ x, const int* __restrict__ perm,
                         const float* __restrict__ vals, float* __restrict__ xt) {
    int i = blockIdx.x, c = threadIdx.x;
    xt[i * DIM + c] = x[(size_t)perm[i] * DIM + c] * tanhf(vals[i]);
}

__global__ void k_gru(const float* __restrict__ xt, const float* __restrict__ W0,
                      const float* __restrict__ w_ih, const float* __restrict__ w_hh,
                      const float* __restrict__ b_ih, const float* __restrict__ b_hh,
                      float* __restrict__ W) {
    __shared__ float sx[DIM], sh[DIM];
    int i = blockIdx.x, c = threadIdx.x;
    sx[c] = xt[i * DIM + c];
    sh[c] = W0[i * DIM + c];
    __syncthreads();
    float gr = b_ih[c], gz = b_ih[DIM + c], gn = b_ih[2 * DIM + c];
    float hr = b_hh[c], hz = b_hh[DIM + c], hn = b_hh[2 * DIM + c];
    const float* wr = w_ih + (size_t)c * DIM;
    const float* wz = w_ih + (size_t)(DIM + c) * DIM;
    const float* wn = w_ih + (size_t)(2 * DIM + c) * DIM;
    const float* ur = w_hh + (size_t)c * DIM;
    const float* uz = w_hh + (size_t)(DIM + c) * DIM;
    const float* un = w_hh + (size_t)(2 * DIM + c) * DIM;
    for (int d = 0; d < DIM; ++d) {
        float xd = sx[d], hd = sh[d];
        gr += xd * wr[d]; gz += xd * wz[d]; gn += xd * wn[d];
        hr += hd * ur[d]; hz += hd * uz[d]; hn += hd * un[d];
    }
    float r = 1.0f / (1.0f + expf(-(gr + hr)));
    float z = 1.0f / (1.0f + expf(-(gz + hz)));
    float nn = tanhf(gn + r * hn);
    W[i * DIM + c] = (1.0f - z) * nn + z * sh[c];
}

// wdeg <- 1.0 (self loop), cnt <- 0
__global__ void k_deg_init(float* __restrict__ wdeg, int* __restrict__ cnt, int n) {
    int i = blockIdx.x * blockDim.x + threadIdx.x;
    if (i < n) { wdeg[i] = 1.0f; cnt[i] = 0; }
}

// weighted degree (for norm) + integer in-degree (for CSR offsets)
__global__ void k_deg_cnt(const int* __restrict__ ei, const float* __restrict__ ew,
                          float* __restrict__ wdeg, int* __restrict__ cnt, int ne) {
    int e = blockIdx.x * blockDim.x + threadIdx.x;
    if (e < ne) {
        int c = ei[ne + e];
        atomicAdd(&wdeg[c], ew[e]);
        atomicAdd(&cnt[c], 1);
    }
}

__global__ void k_dinv(float* __restrict__ deg, int n) {
    int i = blockIdx.x * blockDim.x + threadIdx.x;
    if (i < n) {
        float v = deg[i];
        deg[i] = (v > 0.0f) ? (1.0f / sqrtf(v)) : 0.0f;
    }
}

// ---- 3-phase multi-block exclusive scan of cnt -> offs/cursor ----
__global__ void k_scan1(const int* __restrict__ cnt, int* __restrict__ bsum, int n) {
    __shared__ int red[256];
    int b = blockIdx.x, t = threadIdx.x;
    int chunk = (n + SCAN_B - 1) / SCAN_B;
    int lo = b * chunk;
    int hi = lo + chunk; if (hi > n) hi = n;
    int s = 0;
    for (int i = lo + t; i < hi; i += 256) s += cnt[i];
    red[t] = s;
    __syncthreads();
    for (int off = 128; off > 0; off >>= 1) {
        if (t < off) red[t] += red[t + off];
        __syncthreads();
    }
    if (t == 0) bsum[b] = red[0];
}

__global__ void k_scan2(const int* __restrict__ bsum, int* __restrict__ bbase) {
    __shared__ int s[SCAN_B];
    int t = threadIdx.x;
    s[t] = bsum[t];
    __syncthreads();
    for (int off = 1; off < SCAN_B; off <<= 1) {
        int v = (t >= off) ? s[t - off] : 0;
        __syncthreads();
        s[t] += v;
        __syncthreads();
    }
    bbase[t] = (t > 0) ? s[t - 1] : 0;   // exclusive
    if (t == SCAN_B - 1) bbase[SCAN_B] = s[SCAN_B - 1];  // total
}

__global__ void k_scan3(const int* __restrict__ cnt, const int* __restrict__ bbase,
                        int* __restrict__ offs, int* __restrict__ cursor, int n) {
    __shared__ int red[256];
    int b = blockIdx.x, t = threadIdx.x;
    int chunk = (n + SCAN_B - 1) / SCAN_B;
    int lo = b * chunk;
    int hi = lo + chunk; if (hi > n) hi = n;
    int tchunk = (chunk + 255) / 256;
    int tlo = lo + t * tchunk;
    int thi = tlo + tchunk; if (thi > hi) thi = hi;
    int s = 0;
    for (int i = tlo; i < thi; ++i) s += cnt[i];
    red[t] = s;
    __syncthreads();
    for (int off = 1; off < 256; off <<= 1) {
        int v = (t >= off) ? red[t - off] : 0;
        __syncthreads();
        red[t] += v;
        __syncthreads();
    }
    int run = bbase[b] + ((t > 0) ? red[t - 1] : 0);
    for (int i = tlo; i < thi; ++i) {
        offs[i] = run; cursor[i] = run; run += cnt[i];
    }
    if (b == 0 && t == 0) offs[n] = bbase[SCAN_B];
}

// bucket edges by destination: edata[pos] = {src, norm}
__global__ void k_fill(const int* __restrict__ ei, const float* __restrict__ ew,
                       const float* __restrict__ dinv, int* __restrict__ cursor,
                       int2* __restrict__ edata, int ne) {
    int e = blockIdx.x * blockDim.x + threadIdx.x;
    if (e >= ne) return;
    int r = ei[e], c = ei[ne + e];
    float nrm = dinv[r] * ew[e] * dinv[c];
    int pos = atomicAdd(&cursor[c], 1);
    edata[pos] = make_int2(r, __float_as_int(nrm));
}

// xw = x @ W ; 64x64 block tile, 4x4 per thread, x stored transposed [k][r] in LDS
__global__ __launch_bounds__(256) void k_xw(const float* __restrict__ x,
                                            const float* __restrict__ W,
                                            float* __restrict__ xw, int n) {
    __shared__ float xsT[DIM * 64];  // [k][r]  32KB
    __shared__ float wls[DIM * 64];  // [k][c]  32KB
    int t = threadIdx.x;
    int r0 = blockIdx.x * 64;
    int c0 = blockIdx.y * 64;
    const float4* W4 = (const float4*)W;
#pragma unroll
    for (int it = 0; it < 8; ++it) {
        int id = t + it * 256;
        int k = id >> 4, c4 = id & 15;
        float4 w = W4[k * 32 + (c0 >> 2) + c4];
        *((float4*)&wls[k * 64 + c4 * 4]) = w;
    }
#pragma unroll
    for (int it = 0; it < 8; ++it) {
        int id = t + it * 256;
        int r = id & 63, k4 = id >> 6;
        int row = r0 + r; if (row >= n) row = n - 1;
        float4 v = *((const float4*)&x[(size_t)row * DIM + k4 * 4]);
        xsT[(k4 * 4 + 0) * 64 + r] = v.x;
        xsT[(k4 * 4 + 1) * 64 + r] = v.y;
        xsT[(k4 * 4 + 2) * 64 + r] = v.z;
        xsT[(k4 * 4 + 3) * 64 + r] = v.w;
    }
    __syncthreads();
    int tc = t & 15, tr = t >> 4;
    float acc[4][4];
#pragma unroll
    for (int i = 0; i < 4; ++i)
#pragma unroll
        for (int j = 0; j < 4; ++j) acc[i][j] = 0.0f;
#pragma unroll 4
    for (int k = 0; k < DIM; ++k) {
        float4 xa = *((const float4*)&xsT[k * 64 + tr * 4]);
        float4 wa = *((const float4*)&wls[k * 64 + tc * 4]);
        float xv[4] = {xa.x, xa.y, xa.z, xa.w};
        float wv[4] = {wa.x, wa.y, wa.z, wa.w};
#pragma unroll
        for (int i = 0; i < 4; ++i)
#pragma unroll
            for (int j = 0; j < 4; ++j) acc[i][j] += xv[i] * wv[j];
    }
#pragma unroll
    for (int i = 0; i < 4; ++i) {
        int row = r0 + tr * 4 + i;
        if (row < n) {
            float4 o = {acc[i][0], acc[i][1], acc[i][2], acc[i][3]};
            *((float4*)&xw[(size_t)row * DIM + c0 + tc * 4]) = o;
        }
    }
}

// per-node gather + fused relu-linear head: 32 lanes per node, float4 each
__global__ __launch_bounds__(256) void k_gather(const float* __restrict__ xw,
        const float* __restrict__ dinv, const int* __restrict__ offs,
        const int2* __restrict__ edata, const float* __restrict__ w_lin,
        const float* __restrict__ b_lin, float* __restrict__ out, int n) {
    int gid = blockIdx.x * 256 + threadIdx.x;
    int c = gid >> 5, lane = gid & 31;
    if (c >= n) return;
    const float4* xw4 = (const float4*)xw;
    float dd = dinv[c]; dd *= dd;                      // self-loop norm
    float4 a = xw4[(size_t)c * 32 + lane];
    float4 acc = {a.x * dd, a.y * dd, a.z * dd, a.w * dd};
    int start = offs[c], end = offs[c + 1];
    for (int base = start; base < end; base += 32) {
        int m = end - base; if (m > 32) m = 32;
        int2 ed = (base + lane < end) ? edata[base + lane] : make_int2(0, 0);
        for (int j0 = 0; j0 < m; j0 += 4) {
#pragma unroll
            for (int jj = 0; jj < 4; ++jj) {
                int j = j0 + jj;
                int src = __shfl(ed.x, j, 32);
                float nrm = (j < m) ? __int_as_float(__shfl(ed.y, j, 32)) : 0.0f;
                float4 v = xw4[(size_t)src * 32 + lane];
                acc.x += v.x * nrm; acc.y += v.y * nrm;
                acc.z += v.z * nrm; acc.w += v.w * nrm;
            }
        }
    }
    float4 wl = ((const float4*)w_lin)[lane];
    float r = fmaxf(acc.x, 0.0f) * wl.x + fmaxf(acc.y, 0.0f) * wl.y +
              fmaxf(acc.z, 0.0f) * wl.z + fmaxf(acc.w, 0.0f) * wl.w;
#pragma unroll
    for (int m = 16; m >= 1; m >>= 1) r += __shfl_xor(r, m, 32);
    if (lane == 0) out[c] = r + b_lin[0];
}

extern "C" void kernel_launch(void* const* d_in, const int* in_sizes, int n_in,
                              void* d_out, int out_size, void* d_ws, size_t ws_size,
                              hipStream_t stream) {
    const float* x     = (const float*)d_in[0];
    const int*   ei    = (const int*)d_in[1];
    const float* ew    = (const float*)d_in[2];
    const float* p     = (const float*)d_in[3];
    const float* W0    = (const float*)d_in[4];
    const float* w_ih  = (const float*)d_in[5];
    const float* w_hh  = (const float*)d_in[6];
    const float* b_ih  = (const float*)d_in[7];
    const float* b_hh  = (const float*)d_in[8];
    const float* w_lin = (const float*)d_in[9];
    const float* b_lin = (const float*)d_in[10];
    float* out = (float*)d_out;
    int n  = in_sizes[0] / DIM;
    int ne = in_sizes[2];
    (void)n_in; (void)out_size; (void)ws_size;

    char* base = (char*)d_ws;
    size_t o = 0;
    auto alloc = [&](size_t b) { size_t r = o; o += (b + 255) & ~(size_t)255; return r; };
    float*    score   = (float*)(base + alloc((size_t)n * 4));
    unsigned* hist    = (unsigned*)(base + alloc(65536 * 4));
    unsigned* counter = (unsigned*)(base + alloc(256));
    unsigned* binfo   = (unsigned*)(base + alloc(256));
    float*    cval    = (float*)(base + alloc((size_t)CAP * 4));
    int*      cidx    = (int*)(base + alloc((size_t)CAP * 4));
    int*      perm    = (int*)(base + alloc(TOPK * 4));
    float*    vals    = (float*)(base + alloc(TOPK * 4));
    float*    pinv    = (float*)(base + alloc(256));
    float*    xt      = (float*)(base + alloc(DIM * DIM * 4));
    float*    Wm      = (float*)(base + alloc(DIM * DIM * 4));
    float*    dinv    = (float*)(base + alloc((size_t)n * 4));
    int*      cnt     = (int*)(base + alloc((size_t)n * 4));
    int*      offs    = (int*)(base + alloc((size_t)(n + 1) * 4));
    int*      cursor  = (int*)(base + alloc((size_t)n * 4));
    int*      bsum    = (int*)(base + alloc((SCAN_B + 1) * 4));
    int*      bbase   = (int*)(base + alloc((SCAN_B + 1) * 4));
    int2*     edata   = (int2*)(base + alloc((size_t)ne * 8));
    float*    xw      = (float*)(base + alloc((size_t)n * DIM * 4));

    k_pnorm<<<1, DIM, 0, stream>>>(p, pinv);
    k_score<<<(n + 3) / 4, 256, 0, stream>>>(x, p, pinv, score, n);
    k_zero<<<(65537 + 255) / 256, 256, 0, stream>>>(hist, counter);
    k_hist<<<(n + 255) / 256, 256, 0, stream>>>(score, hist, n);
    k_findbin<<<1, 1024, 0, stream>>>(hist, binfo, TOPK);
    k_collect<<<(n + 255) / 256, 256, 0, stream>>>(score, binfo, counter, cval, cidx, n);
    k_rank<<<(CAP + 255) / 256, 256, 0, stream>>>(cval, cidx, counter, perm, vals, TOPK);
    k_xtilde<<<DIM, DIM, 0, stream>>>(x, perm, vals, xt);
    k_gru<<<DIM, DIM, 0, stream>>>(xt, W0, w_ih, w_hh, b_ih, b_hh, Wm);
    k_deg_init<<<(n + 255) / 256, 256, 0, stream>>>(dinv, cnt, n);
    k_deg_cnt<<<(ne + 255) / 256, 256, 0, stream>>>(ei, ew, dinv, cnt, ne);
    k_dinv<<<(n + 255) / 256, 256, 0, stream>>>(dinv, n);
    k_scan1<<<SCAN_B, 256, 0, stream>>>(cnt, bsum, n);
    k_scan2<<<1, SCAN_B, 0, stream>>>(bsum, bbase);
    k_scan3<<<SCAN_B, 256, 0, stream>>>(cnt, bbase, offs, cursor, n);
    k_fill<<<(ne + 255) / 256, 256, 0, stream>>>(ei, ew, dinv, cursor, edata, ne);
    dim3 gxw((n + 63) / 64, 2);
    k_xw<<<gxw, 256, 0, stream>>>(x, Wm, xw, n);
    long long g_threads = (long long)n * 32;
    k_gather<<<(int)((g_threads + 255) / 256), 256, 0, stream>>>(
        xw, dinv, offs, edata, w_lin, b_lin, out, n);
}

// Round 5
// 409.511 us; speedup vs baseline: 7.6819x; 1.3054x over previous
//
#include <hip/hip_runtime.h>
#include <hip/hip_bf16.h>
#include <math.h>

#define DIM 128
#define TOPK 128
#define CAP 4096
#define SCAN_B 256

__device__ __forceinline__ unsigned f2k(float f) {
    unsigned b = __float_as_uint(f);
    return (b & 0x80000000u) ? ~b : (b | 0x80000000u);
}

__global__ void k_pnorm(const float* __restrict__ p, float* __restrict__ pinv) {
    __shared__ float s[DIM];
    int t = threadIdx.x;
    float v = p[t];
    s[t] = v * v;
    __syncthreads();
    for (int off = 64; off > 0; off >>= 1) {
        if (t < off) s[t] += s[t + off];
        __syncthreads();
    }
    if (t == 0) pinv[0] = 1.0f / sqrtf(s[0]);
}

// wave (64 lanes) per node, float2 per lane
__global__ void k_score(const float* __restrict__ x, const float* __restrict__ p,
                        const float* __restrict__ pinv, float* __restrict__ score, int n) {
    int lane = threadIdx.x & 63;
    int node = blockIdx.x * 4 + (threadIdx.x >> 6);
    if (node >= n) return;
    const float2* x2 = (const float2*)(x) + (size_t)node * 64;
    const float2* p2 = (const float2*)p;
    float2 a = x2[lane], b = p2[lane];
    float acc = a.x * b.x + a.y * b.y;
#pragma unroll
    for (int m = 32; m >= 1; m >>= 1) acc += __shfl_xor(acc, m, 64);
    if (lane == 0) score[node] = acc * pinv[0];
}

__global__ void k_zero(unsigned* __restrict__ hist, unsigned* __restrict__ counter) {
    int i = blockIdx.x * blockDim.x + threadIdx.x;
    if (i < 65536) hist[i] = 0u;
    if (i == 0) counter[0] = 0u;
}

__global__ void k_hist(const float* __restrict__ score, unsigned* __restrict__ hist, int n) {
    int i = blockIdx.x * blockDim.x + threadIdx.x;
    if (i < n) atomicAdd(&hist[f2k(score[i]) >> 16], 1u);
}

// find bin b* with cnt_above(b*) < k <= cnt_above(b*) + hist[b*]
__global__ void k_findbin(const unsigned* __restrict__ hist, unsigned* __restrict__ binfo, int k) {
    __shared__ unsigned csum[1024];
    int t = threadIdx.x;
    unsigned s = 0;
    for (int j = 0; j < 64; ++j) s += hist[t * 64 + j];
    csum[t] = s;
    __syncthreads();
    for (int off = 1; off < 1024; off <<= 1) {
        unsigned v = (t + off < 1024) ? csum[t + off] : 0u;
        __syncthreads();
        csum[t] += v;
        __syncthreads();
    }
    unsigned run = (t + 1 < 1024) ? csum[t + 1] : 0u;   // count in bins > t*64+63
    for (int j = 63; j >= 0; --j) {
        unsigned h = hist[t * 64 + j];
        if (h > 0u && run < (unsigned)k && run + h >= (unsigned)k) {
            binfo[0] = (unsigned)(t * 64 + j);
            binfo[1] = run;
        }
        run += h;
    }
}

__global__ void k_collect(const float* __restrict__ score, const unsigned* __restrict__ binfo,
                          unsigned* __restrict__ counter, float* __restrict__ cval,
                          int* __restrict__ cidx, int n) {
    int i = blockIdx.x * blockDim.x + threadIdx.x;
    if (i >= n) return;
    float s = score[i];
    if ((f2k(s) >> 16) >= binfo[0]) {
        unsigned pos = atomicAdd(counter, 1u);
        if (pos < CAP) { cval[pos] = s; cidx[pos] = i; }
    }
}

// rank-based exact top-k: rank = #{j : v_j > v_i || (v_j==v_i && id_j < id_i)}
// matches jax.lax.top_k (sorted desc, lower index wins ties). No barriers.
__global__ void k_rank(const float* __restrict__ cval, const int* __restrict__ cidx,
                       const unsigned* __restrict__ counter, int* __restrict__ perm,
                       float* __restrict__ vals, int k) {
    int i = blockIdx.x * blockDim.x + threadIdx.x;
    unsigned cnt = counter[0];
    int m = (cnt < (unsigned)CAP) ? (int)cnt : CAP;
    if (i >= m) return;
    float v = cval[i]; int id = cidx[i];
    int rank = 0;
    for (int j = 0; j < m; ++j) {
        float vj = cval[j]; int ij = cidx[j];
        if (vj > v || (vj == v && ij < id)) ++rank;
    }
    if (rank < k) { perm[rank] = id; vals[rank] = v; }
}

__global__ void k_xtilde(const float* __restrict__ x, const int* __restrict__ perm,
                         const float* __restrict__ vals, float* __restrict__ xt) {
    int i = blockIdx.x, c = threadIdx.x;
    xt[i * DIM + c] = x[(size_t)perm[i] * DIM + c] * tanhf(vals[i]);
}

__global__ void k_gru(const float* __restrict__ xt, const float* __restrict__ W0,
                      const float* __restrict__ w_ih, const float* __restrict__ w_hh,
                      const float* __restrict__ b_ih, const float* __restrict__ b_hh,
                      float* __restrict__ W) {
    __shared__ float sx[DIM], sh[DIM];
    int i = blockIdx.x, c = threadIdx.x;
    sx[c] = xt[i * DIM + c];
    sh[c] = W0[i * DIM + c];
    __syncthreads();
    float gr = b_ih[c], gz = b_ih[DIM + c], gn = b_ih[2 * DIM + c];
    float hr = b_hh[c], hz = b_hh[DIM + c], hn = b_hh[2 * DIM + c];
    const float* wr = w_ih + (size_t)c * DIM;
    const float* wz = w_ih + (size_t)(DIM + c) * DIM;
    const float* wn = w_ih + (size_t)(2 * DIM + c) * DIM;
    const float* ur = w_hh + (size_t)c * DIM;
    const float* uz = w_hh + (size_t)(DIM + c) * DIM;
    const float* un = w_hh + (size_t)(2 * DIM + c) * DIM;
    for (int d = 0; d < DIM; ++d) {
        float xd = sx[d], hd = sh[d];
        gr += xd * wr[d]; gz += xd * wz[d]; gn += xd * wn[d];
        hr += hd * ur[d]; hz += hd * uz[d]; hn += hd * un[d];
    }
    float r = 1.0f / (1.0f + expf(-(gr + hr)));
    float z = 1.0f / (1.0f + expf(-(gz + hz)));
    float nn = tanhf(gn + r * hn);
    W[i * DIM + c] = (1.0f - z) * nn + z * sh[c];
}

// packed degree accumulator: [63:40] in-count, [39:0] fixed-point sum (2^-32)
__global__ void k_dc_zero(unsigned long long* __restrict__ packed, int n) {
    int i = blockIdx.x * blockDim.x + threadIdx.x;
    if (i < n) packed[i] = 0ull;
}

// one u64 atomic per edge; returned old value gives per-destination sequence
__global__ void k_deg_cnt2(const int* __restrict__ ei, const float* __restrict__ ew,
                           unsigned long long* __restrict__ packed,
                           int* __restrict__ eseq, int ne) {
    int e = blockIdx.x * blockDim.x + threadIdx.x;
    if (e >= ne) return;
    int c = ei[ne + e];
    float w = ew[e];
    unsigned long long fx = (unsigned long long)((double)w * 4294967296.0);
    unsigned long long add = (1ull << 40) | fx;
    unsigned long long old = atomicAdd(&packed[c], add);
    eseq[e] = (int)(old >> 40);
}

// unpack: dinv = rsqrt(1 + sum_w), cnt = in-count
__global__ void k_dinv2(const unsigned long long* __restrict__ packed,
                        float* __restrict__ dinv, int* __restrict__ cnt, int n) {
    int i = blockIdx.x * blockDim.x + threadIdx.x;
    if (i < n) {
        unsigned long long pk = packed[i];
        float sumw = (float)((double)(pk & ((1ull << 40) - 1ull)) * (1.0 / 4294967296.0));
        float deg = 1.0f + sumw;   // self-loop weight 1, deg > 0 always
        dinv[i] = rsqrtf(deg);
        cnt[i] = (int)(pk >> 40);
    }
}

// ---- 3-phase multi-block exclusive scan of cnt -> offs ----
__global__ void k_scan1(const int* __restrict__ cnt, int* __restrict__ bsum, int n) {
    __shared__ int red[256];
    int b = blockIdx.x, t = threadIdx.x;
    int chunk = (n + SCAN_B - 1) / SCAN_B;
    int lo = b * chunk;
    int hi = lo + chunk; if (hi > n) hi = n;
    int s = 0;
    for (int i = lo + t; i < hi; i += 256) s += cnt[i];
    red[t] = s;
    __syncthreads();
    for (int off = 128; off > 0; off >>= 1) {
        if (t < off) red[t] += red[t + off];
        __syncthreads();
    }
    if (t == 0) bsum[b] = red[0];
}

__global__ void k_scan2(const int* __restrict__ bsum, int* __restrict__ bbase) {
    __shared__ int s[SCAN_B];
    int t = threadIdx.x;
    s[t] = bsum[t];
    __syncthreads();
    for (int off = 1; off < SCAN_B; off <<= 1) {
        int v = (t >= off) ? s[t - off] : 0;
        __syncthreads();
        s[t] += v;
        __syncthreads();
    }
    bbase[t] = (t > 0) ? s[t - 1] : 0;   // exclusive
    if (t == SCAN_B - 1) bbase[SCAN_B] = s[SCAN_B - 1];  // total
}

__global__ void k_scan3(const int* __restrict__ cnt, const int* __restrict__ bbase,
                        int* __restrict__ offs, int n) {
    __shared__ int red[256];
    int b = blockIdx.x, t = threadIdx.x;
    int chunk = (n + SCAN_B - 1) / SCAN_B;
    int lo = b * chunk;
    int hi = lo + chunk; if (hi > n) hi = n;
    int tchunk = (chunk + 255) / 256;
    int tlo = lo + t * tchunk;
    int thi = tlo + tchunk; if (thi > hi) thi = hi;
    int s = 0;
    for (int i = tlo; i < thi; ++i) s += cnt[i];
    red[t] = s;
    __syncthreads();
    for (int off = 1; off < 256; off <<= 1) {
        int v = (t >= off) ? red[t - off] : 0;
        __syncthreads();
        red[t] += v;
        __syncthreads();
    }
    int run = bbase[b] + ((t > 0) ? red[t - 1] : 0);
    for (int i = tlo; i < thi; ++i) {
        offs[i] = run; run += cnt[i];
    }
    if (b == 0 && t == 0) offs[n] = bbase[SCAN_B];
}

// bucket edges by destination, atomic-free: pos = offs[c] + eseq[e]
__global__ void k_fill(const int* __restrict__ ei, const float* __restrict__ ew,
                       const float* __restrict__ dinv, const int* __restrict__ offs,
                       const int* __restrict__ eseq, int2* __restrict__ edata, int ne) {
    int e = blockIdx.x * blockDim.x + threadIdx.x;
    if (e >= ne) return;
    int r = ei[e], c = ei[ne + e];
    float nrm = dinv[r] * ew[e] * dinv[c];
    int pos = offs[c] + eseq[e];
    edata[pos] = make_int2(r, __float_as_int(nrm));
}

// xw = x @ W ; 64x64 block tile, 4x4 per thread, x stored transposed [k][r] in LDS
__global__ __launch_bounds__(256) void k_xw(const float* __restrict__ x,
                                            const float* __restrict__ W,
                                            float* __restrict__ xw, int n) {
    __shared__ float xsT[DIM * 64];  // [k][r]  32KB
    __shared__ float wls[DIM * 64];  // [k][c]  32KB
    int t = threadIdx.x;
    int r0 = blockIdx.x * 64;
    int c0 = blockIdx.y * 64;
    const float4* W4 = (const float4*)W;
#pragma unroll
    for (int it = 0; it < 8; ++it) {
        int id = t + it * 256;
        int k = id >> 4, c4 = id & 15;
        float4 w = W4[k * 32 + (c0 >> 2) + c4];
        *((float4*)&wls[k * 64 + c4 * 4]) = w;
    }
#pragma unroll
    for (int it = 0; it < 8; ++it) {
        int id = t + it * 256;
        int r = id & 63, k4 = id >> 6;
        int row = r0 + r; if (row >= n) row = n - 1;
        float4 v = *((const float4*)&x[(size_t)row * DIM + k4 * 4]);
        xsT[(k4 * 4 + 0) * 64 + r] = v.x;
        xsT[(k4 * 4 + 1) * 64 + r] = v.y;
        xsT[(k4 * 4 + 2) * 64 + r] = v.z;
        xsT[(k4 * 4 + 3) * 64 + r] = v.w;
    }
    __syncthreads();
    int tc = t & 15, tr = t >> 4;
    float acc[4][4];
#pragma unroll
    for (int i = 0; i < 4; ++i)
#pragma unroll
        for (int j = 0; j < 4; ++j) acc[i][j] = 0.0f;
#pragma unroll 4
    for (int k = 0; k < DIM; ++k) {
        float4 xa = *((const float4*)&xsT[k * 64 + tr * 4]);
        float4 wa = *((const float4*)&wls[k * 64 + tc * 4]);
        float xv[4] = {xa.x, xa.y, xa.z, xa.w};
        float wv[4] = {wa.x, wa.y, wa.z, wa.w};
#pragma unroll
        for (int i = 0; i < 4; ++i)
#pragma unroll
            for (int j = 0; j < 4; ++j) acc[i][j] += xv[i] * wv[j];
    }
#pragma unroll
    for (int i = 0; i < 4; ++i) {
        int row = r0 + tr * 4 + i;
        if (row < n) {
            float4 o = {acc[i][0], acc[i][1], acc[i][2], acc[i][3]};
            *((float4*)&xw[(size_t)row * DIM + c0 + tc * 4]) = o;
        }
    }
}

// per-node gather + fused relu-linear head: 32 lanes per node, float4 each
__global__ __launch_bounds__(256) void k_gather(const float* __restrict__ xw,
        const float* __restrict__ dinv, const int* __restrict__ offs,
        const int2* __restrict__ edata, const float* __restrict__ w_lin,
        const float* __restrict__ b_lin, float* __restrict__ out, int n) {
    int gid = blockIdx.x * 256 + threadIdx.x;
    int c = gid >> 5, lane = gid & 31;
    if (c >= n) return;
    const float4* xw4 = (const float4*)xw;
    float dd = dinv[c]; dd *= dd;                      // self-loop norm
    float4 a = xw4[(size_t)c * 32 + lane];
    float4 acc = {a.x * dd, a.y * dd, a.z * dd, a.w * dd};
    int start = offs[c], end = offs[c + 1];
    for (int base = start; base < end; base += 32) {
        int m = end - base; if (m > 32) m = 32;
        int2 ed = (base + lane < end) ? edata[base + lane] : make_int2(0, 0);
        for (int j0 = 0; j0 < m; j0 += 4) {
#pragma unroll
            for (int jj = 0; jj < 4; ++jj) {
                int j = j0 + jj;
                int src = __shfl(ed.x, j, 32);
                float nrm = (j < m) ? __int_as_float(__shfl(ed.y, j, 32)) : 0.0f;
                float4 v = xw4[(size_t)src * 32 + lane];
                acc.x += v.x * nrm; acc.y += v.y * nrm;
                acc.z += v.z * nrm; acc.w += v.w * nrm;
            }
        }
    }
    float4 wl = ((const float4*)w_lin)[lane];
    float r = fmaxf(acc.x, 0.0f) * wl.x + fmaxf(acc.y, 0.0f) * wl.y +
              fmaxf(acc.z, 0.0f) * wl.z + fmaxf(acc.w, 0.0f) * wl.w;
#pragma unroll
    for (int m = 16; m >= 1; m >>= 1) r += __shfl_xor(r, m, 32);
    if (lane == 0) out[c] = r + b_lin[0];
}

extern "C" void kernel_launch(void* const* d_in, const int* in_sizes, int n_in,
                              void* d_out, int out_size, void* d_ws, size_t ws_size,
                              hipStream_t stream) {
    const float* x     = (const float*)d_in[0];
    const int*   ei    = (const int*)d_in[1];
    const float* ew    = (const float*)d_in[2];
    const float* p     = (const float*)d_in[3];
    const float* W0    = (const float*)d_in[4];
    const float* w_ih  = (const float*)d_in[5];
    const float* w_hh  = (const float*)d_in[6];
    const float* b_ih  = (const float*)d_in[7];
    const float* b_hh  = (const float*)d_in[8];
    const float* w_lin = (const float*)d_in[9];
    const float* b_lin = (const float*)d_in[10];
    float* out = (float*)d_out;
    int n  = in_sizes[0] / DIM;
    int ne = in_sizes[2];
    (void)n_in; (void)out_size; (void)ws_size;

    char* base = (char*)d_ws;
    size_t o = 0;
    auto alloc = [&](size_t b) { size_t r = o; o += (b + 255) & ~(size_t)255; return r; };
    float*    score   = (float*)(base + alloc((size_t)n * 4));
    unsigned* hist    = (unsigned*)(base + alloc(65536 * 4));
    unsigned* counter = (unsigned*)(base + alloc(256));
    unsigned* binfo   = (unsigned*)(base + alloc(256));
    float*    cval    = (float*)(base + alloc((size_t)CAP * 4));
    int*      cidx    = (int*)(base + alloc((size_t)CAP * 4));
    int*      perm    = (int*)(base + alloc(TOPK * 4));
    float*    vals    = (float*)(base + alloc(TOPK * 4));
    float*    pinv    = (float*)(base + alloc(256));
    float*    xt      = (float*)(base + alloc(DIM * DIM * 4));
    float*    Wm      = (float*)(base + alloc(DIM * DIM * 4));
    float*    dinv    = (float*)(base + alloc((size_t)n * 4));
    int*      cnt     = (int*)(base + alloc((size_t)n * 4));
    int*      offs    = (int*)(base + alloc((size_t)(n + 1) * 4));
    unsigned long long* packed = (unsigned long long*)(base + alloc((size_t)n * 8));
    int*      eseq    = (int*)(base + alloc((size_t)ne * 4));
    int*      bsum    = (int*)(base + alloc((SCAN_B + 1) * 4));
    int*      bbase   = (int*)(base + alloc((SCAN_B + 1) * 4));
    int2*     edata   = (int2*)(base + alloc((size_t)ne * 8));
    float*    xw      = (float*)(base + alloc((size_t)n * DIM * 4));

    k_pnorm<<<1, DIM, 0, stream>>>(p, pinv);
    k_score<<<(n + 3) / 4, 256, 0, stream>>>(x, p, pinv, score, n);
    k_zero<<<(65537 + 255) / 256, 256, 0, stream>>>(hist, counter);
    k_hist<<<(n + 255) / 256, 256, 0, stream>>>(score, hist, n);
    k_findbin<<<1, 1024, 0, stream>>>(hist, binfo, TOPK);
    k_collect<<<(n + 255) / 256, 256, 0, stream>>>(score, binfo, counter, cval, cidx, n);
    k_rank<<<(CAP + 255) / 256, 256, 0, stream>>>(cval, cidx, counter, perm, vals, TOPK);
    k_xtilde<<<DIM, DIM, 0, stream>>>(x, perm, vals, xt);
    k_gru<<<DIM, DIM, 0, stream>>>(xt, W0, w_ih, w_hh, b_ih, b_hh, Wm);
    k_dc_zero<<<(n + 255) / 256, 256, 0, stream>>>(packed, n);
    k_deg_cnt2<<<(ne + 255) / 256, 256, 0, stream>>>(ei, ew, packed, eseq, ne);
    k_dinv2<<<(n + 255) / 256, 256, 0, stream>>>(packed, dinv, cnt, n);
    k_scan1<<<SCAN_B, 256, 0, stream>>>(cnt, bsum, n);
    k_scan2<<<1, SCAN_B, 0, stream>>>(bsum, bbase);
    k_scan3<<<SCAN_B, 256, 0, stream>>>(cnt, bbase, offs, n);
    k_fill<<<(ne + 255) / 256, 256, 0, stream>>>(ei, ew, dinv, offs, eseq, edata, ne);
    dim3 gxw((n + 63) / 64, 2);
    k_xw<<<gxw, 256, 0, stream>>>(x, Wm, xw, n);
    long long g_threads = (long long)n * 32;
    k_gather<<<(int)((g_threads + 255) / 256), 256, 0, stream>>>(
        xw, dinv, offs, edata, w_lin, b_lin, out, n);
}

// Round 6
// 353.529 us; speedup vs baseline: 8.8983x; 1.1584x over previous
//
#include <hip/hip_runtime.h>
#include <hip/hip_bf16.h>
#include <math.h>

#define DIM 128
#define TOPK 128
#define CAP 4096
#define SCAN_B 256

__device__ __forceinline__ unsigned f2k(float f) {
    unsigned b = __float_as_uint(f);
    return (b & 0x80000000u) ? ~b : (b | 0x80000000u);
}

// round-to-nearest-even bf16 (as high 16 bits of fp32)
__device__ __forceinline__ unsigned bf16rn(float v) {
    unsigned u = __float_as_uint(v);
    u += 0x7fffu + ((u >> 16) & 1u);
    return u >> 16;
}

__global__ void k_pnorm(const float* __restrict__ p, float* __restrict__ pinv) {
    __shared__ float s[DIM];
    int t = threadIdx.x;
    float v = p[t];
    s[t] = v * v;
    __syncthreads();
    for (int off = 64; off > 0; off >>= 1) {
        if (t < off) s[t] += s[t + off];
        __syncthreads();
    }
    if (t == 0) pinv[0] = 1.0f / sqrtf(s[0]);
}

// wave (64 lanes) per node, float2 per lane
__global__ void k_score(const float* __restrict__ x, const float* __restrict__ p,
                        const float* __restrict__ pinv, float* __restrict__ score, int n) {
    int lane = threadIdx.x & 63;
    int node = blockIdx.x * 4 + (threadIdx.x >> 6);
    if (node >= n) return;
    const float2* x2 = (const float2*)(x) + (size_t)node * 64;
    const float2* p2 = (const float2*)p;
    float2 a = x2[lane], b = p2[lane];
    float acc = a.x * b.x + a.y * b.y;
#pragma unroll
    for (int m = 32; m >= 1; m >>= 1) acc += __shfl_xor(acc, m, 64);
    if (lane == 0) score[node] = acc * pinv[0];
}

// zero hist + counter + packed degree accumulators in one pass
__global__ void k_zero(unsigned* __restrict__ hist, unsigned* __restrict__ counter,
                       unsigned long long* __restrict__ packed, int n) {
    int i = blockIdx.x * blockDim.x + threadIdx.x;
    if (i < 65536) hist[i] = 0u;
    if (i == 0) counter[0] = 0u;
    if (i < n) packed[i] = 0ull;
}

__global__ void k_hist(const float* __restrict__ score, unsigned* __restrict__ hist, int n) {
    int i = blockIdx.x * blockDim.x + threadIdx.x;
    if (i < n) atomicAdd(&hist[f2k(score[i]) >> 16], 1u);
}

// find bin b* with cnt_above(b*) < k <= cnt_above(b*) + hist[b*]
__global__ void k_findbin(const unsigned* __restrict__ hist, unsigned* __restrict__ binfo, int k) {
    __shared__ unsigned csum[1024];
    int t = threadIdx.x;
    unsigned s = 0;
    for (int j = 0; j < 64; ++j) s += hist[t * 64 + j];
    csum[t] = s;
    __syncthreads();
    for (int off = 1; off < 1024; off <<= 1) {
        unsigned v = (t + off < 1024) ? csum[t + off] : 0u;
        __syncthreads();
        csum[t] += v;
        __syncthreads();
    }
    unsigned run = (t + 1 < 1024) ? csum[t + 1] : 0u;   // count in bins > t*64+63
    for (int j = 63; j >= 0; --j) {
        unsigned h = hist[t * 64 + j];
        if (h > 0u && run < (unsigned)k && run + h >= (unsigned)k) {
            binfo[0] = (unsigned)(t * 64 + j);
            binfo[1] = run;
        }
        run += h;
    }
}

__global__ void k_collect(const float* __restrict__ score, const unsigned* __restrict__ binfo,
                          unsigned* __restrict__ counter, float* __restrict__ cval,
                          int* __restrict__ cidx, int n) {
    int i = blockIdx.x * blockDim.x + threadIdx.x;
    if (i >= n) return;
    float s = score[i];
    if ((f2k(s) >> 16) >= binfo[0]) {
        unsigned pos = atomicAdd(counter, 1u);
        if (pos < CAP) { cval[pos] = s; cidx[pos] = i; }
    }
}

// rank-based exact top-k: rank = #{j : v_j > v_i || (v_j==v_i && id_j < id_i)}
__global__ void k_rank(const float* __restrict__ cval, const int* __restrict__ cidx,
                       const unsigned* __restrict__ counter, int* __restrict__ perm,
                       float* __restrict__ vals, int k) {
    int i = blockIdx.x * blockDim.x + threadIdx.x;
    unsigned cnt = counter[0];
    int m = (cnt < (unsigned)CAP) ? (int)cnt : CAP;
    if (i >= m) return;
    float v = cval[i]; int id = cidx[i];
    int rank = 0;
    for (int j = 0; j < m; ++j) {
        float vj = cval[j]; int ij = cidx[j];
        if (vj > v || (vj == v && ij < id)) ++rank;
    }
    if (rank < k) { perm[rank] = id; vals[rank] = v; }
}

// GRU with fused x_tilde: sx = x[perm[i]] * tanh(vals[i])
__global__ void k_gru(const float* __restrict__ x, const int* __restrict__ perm,
                      const float* __restrict__ vals, const float* __restrict__ W0,
                      const float* __restrict__ w_ih, const float* __restrict__ w_hh,
                      const float* __restrict__ b_ih, const float* __restrict__ b_hh,
                      float* __restrict__ W) {
    __shared__ float sx[DIM], sh[DIM];
    int i = blockIdx.x, c = threadIdx.x;
    sx[c] = x[(size_t)perm[i] * DIM + c] * tanhf(vals[i]);
    sh[c] = W0[i * DIM + c];
    __syncthreads();
    float gr = b_ih[c], gz = b_ih[DIM + c], gn = b_ih[2 * DIM + c];
    float hr = b_hh[c], hz = b_hh[DIM + c], hn = b_hh[2 * DIM + c];
    const float* wr = w_ih + (size_t)c * DIM;
    const float* wz = w_ih + (size_t)(DIM + c) * DIM;
    const float* wn = w_ih + (size_t)(2 * DIM + c) * DIM;
    const float* ur = w_hh + (size_t)c * DIM;
    const float* uz = w_hh + (size_t)(DIM + c) * DIM;
    const float* un = w_hh + (size_t)(2 * DIM + c) * DIM;
    for (int d = 0; d < DIM; ++d) {
        float xd = sx[d], hd = sh[d];
        gr += xd * wr[d]; gz += xd * wz[d]; gn += xd * wn[d];
        hr += hd * ur[d]; hz += hd * uz[d]; hn += hd * un[d];
    }
    float r = 1.0f / (1.0f + expf(-(gr + hr)));
    float z = 1.0f / (1.0f + expf(-(gz + hz)));
    float nn = tanhf(gn + r * hn);
    W[i * DIM + c] = (1.0f - z) * nn + z * sh[c];
}

// one u64 atomic per edge; returned old value gives per-destination sequence
__global__ void k_deg_cnt2(const int* __restrict__ ei, const float* __restrict__ ew,
                           unsigned long long* __restrict__ packed,
                           int* __restrict__ eseq, int ne) {
    int e = blockIdx.x * blockDim.x + threadIdx.x;
    if (e >= ne) return;
    int c = ei[ne + e];
    float w = ew[e];
    unsigned long long fx = (unsigned long long)((double)w * 4294967296.0);
    unsigned long long add = (1ull << 40) | fx;
    unsigned long long old = atomicAdd(&packed[c], add);
    eseq[e] = (int)(old >> 40);
}

// unpack: dinv = rsqrt(1 + sum_w), cnt = in-count
__global__ void k_dinv2(const unsigned long long* __restrict__ packed,
                        float* __restrict__ dinv, int* __restrict__ cnt, int n) {
    int i = blockIdx.x * blockDim.x + threadIdx.x;
    if (i < n) {
        unsigned long long pk = packed[i];
        float sumw = (float)((double)(pk & ((1ull << 40) - 1ull)) * (1.0 / 4294967296.0));
        float deg = 1.0f + sumw;   // self-loop weight 1, deg > 0 always
        dinv[i] = rsqrtf(deg);
        cnt[i] = (int)(pk >> 40);
    }
}

// ---- 3-phase multi-block exclusive scan of cnt -> offs ----
__global__ void k_scan1(const int* __restrict__ cnt, int* __restrict__ bsum, int n) {
    __shared__ int red[256];
    int b = blockIdx.x, t = threadIdx.x;
    int chunk = (n + SCAN_B - 1) / SCAN_B;
    int lo = b * chunk;
    int hi = lo + chunk; if (hi > n) hi = n;
    int s = 0;
    for (int i = lo + t; i < hi; i += 256) s += cnt[i];
    red[t] = s;
    __syncthreads();
    for (int off = 128; off > 0; off >>= 1) {
        if (t < off) red[t] += red[t + off];
        __syncthreads();
    }
    if (t == 0) bsum[b] = red[0];
}

__global__ void k_scan2(const int* __restrict__ bsum, int* __restrict__ bbase) {
    __shared__ int s[SCAN_B];
    int t = threadIdx.x;
    s[t] = bsum[t];
    __syncthreads();
    for (int off = 1; off < SCAN_B; off <<= 1) {
        int v = (t >= off) ? s[t - off] : 0;
        __syncthreads();
        s[t] += v;
        __syncthreads();
    }
    bbase[t] = (t > 0) ? s[t - 1] : 0;   // exclusive
    if (t == SCAN_B - 1) bbase[SCAN_B] = s[SCAN_B - 1];  // total
}

__global__ void k_scan3(const int* __restrict__ cnt, const int* __restrict__ bbase,
                        int* __restrict__ offs, int n) {
    __shared__ int red[256];
    int b = blockIdx.x, t = threadIdx.x;
    int chunk = (n + SCAN_B - 1) / SCAN_B;
    int lo = b * chunk;
    int hi = lo + chunk; if (hi > n) hi = n;
    int tchunk = (chunk + 255) / 256;
    int tlo = lo + t * tchunk;
    int thi = tlo + tchunk; if (thi > hi) thi = hi;
    int s = 0;
    for (int i = tlo; i < thi; ++i) s += cnt[i];
    red[t] = s;
    __syncthreads();
    for (int off = 1; off < 256; off <<= 1) {
        int v = (t >= off) ? red[t - off] : 0;
        __syncthreads();
        red[t] += v;
        __syncthreads();
    }
    int run = bbase[b] + ((t > 0) ? red[t - 1] : 0);
    for (int i = tlo; i < thi; ++i) {
        offs[i] = run; run += cnt[i];
    }
    if (b == 0 && t == 0) offs[n] = bbase[SCAN_B];
}

// bucket edges by destination, atomic-free: pos = offs[c] + eseq[e]
__global__ void k_fill(const int* __restrict__ ei, const float* __restrict__ ew,
                       const float* __restrict__ dinv, const int* __restrict__ offs,
                       const int* __restrict__ eseq, int2* __restrict__ edata, int ne) {
    int e = blockIdx.x * blockDim.x + threadIdx.x;
    if (e >= ne) return;
    int r = ei[e], c = ei[ne + e];
    float nrm = dinv[r] * ew[e] * dinv[c];
    int pos = offs[c] + eseq[e];
    edata[pos] = make_int2(r, __float_as_int(nrm));
}

// xw = x @ W -> bf16 ; 64x64 block tile, 4x4 per thread, x transposed [k][r] in LDS
__global__ __launch_bounds__(256) void k_xw(const float* __restrict__ x,
                                            const float* __restrict__ W,
                                            unsigned short* __restrict__ xwh, int n) {
    __shared__ float xsT[DIM * 64];  // [k][r]  32KB
    __shared__ float wls[DIM * 64];  // [k][c]  32KB
    int t = threadIdx.x;
    int r0 = blockIdx.x * 64;
    int c0 = blockIdx.y * 64;
    const float4* W4 = (const float4*)W;
#pragma unroll
    for (int it = 0; it < 8; ++it) {
        int id = t + it * 256;
        int k = id >> 4, c4 = id & 15;
        float4 w = W4[k * 32 + (c0 >> 2) + c4];
        *((float4*)&wls[k * 64 + c4 * 4]) = w;
    }
#pragma unroll
    for (int it = 0; it < 8; ++it) {
        int id = t + it * 256;
        int r = id & 63, k4 = id >> 6;
        int row = r0 + r; if (row >= n) row = n - 1;
        float4 v = *((const float4*)&x[(size_t)row * DIM + k4 * 4]);
        xsT[(k4 * 4 + 0) * 64 + r] = v.x;
        xsT[(k4 * 4 + 1) * 64 + r] = v.y;
        xsT[(k4 * 4 + 2) * 64 + r] = v.z;
        xsT[(k4 * 4 + 3) * 64 + r] = v.w;
    }
    __syncthreads();
    int tc = t & 15, tr = t >> 4;
    float acc[4][4];
#pragma unroll
    for (int i = 0; i < 4; ++i)
#pragma unroll
        for (int j = 0; j < 4; ++j) acc[i][j] = 0.0f;
#pragma unroll 4
    for (int k = 0; k < DIM; ++k) {
        float4 xa = *((const float4*)&xsT[k * 64 + tr * 4]);
        float4 wa = *((const float4*)&wls[k * 64 + tc * 4]);
        float xv[4] = {xa.x, xa.y, xa.z, xa.w};
        float wv[4] = {wa.x, wa.y, wa.z, wa.w};
#pragma unroll
        for (int i = 0; i < 4; ++i)
#pragma unroll
            for (int j = 0; j < 4; ++j) acc[i][j] += xv[i] * wv[j];
    }
#pragma unroll
    for (int i = 0; i < 4; ++i) {
        int row = r0 + tr * 4 + i;
        if (row < n) {
            uint2 o;
            o.x = (bf16rn(acc[i][1]) << 16) | bf16rn(acc[i][0]);
            o.y = (bf16rn(acc[i][3]) << 16) | bf16rn(acc[i][2]);
            *((uint2*)&xwh[(size_t)row * DIM + c0 + tc * 4]) = o;
        }
    }
}

// per-node gather + fused relu-linear head: 16 lanes per node, 8 bf16 (16B) each
__global__ __launch_bounds__(256) void k_gather(const unsigned short* __restrict__ xwh,
        const float* __restrict__ dinv, const int* __restrict__ offs,
        const int2* __restrict__ edata, const float* __restrict__ w_lin,
        const float* __restrict__ b_lin, float* __restrict__ out, int n) {
    int gid = blockIdx.x * 256 + threadIdx.x;
    int c = gid >> 4, lane = gid & 15;
    if (c >= n) return;
    const uint4* xw4 = (const uint4*)xwh;    // 8 bf16 per uint4; 16 uint4 per row
    float dd = dinv[c]; dd *= dd;            // self-loop norm
    float acc[8];
    {
        uint4 a = xw4[(size_t)c * 16 + lane];
        unsigned w[4] = {a.x, a.y, a.z, a.w};
#pragma unroll
        for (int q = 0; q < 4; ++q) {
            acc[2 * q]     = __uint_as_float(w[q] << 16) * dd;
            acc[2 * q + 1] = __uint_as_float(w[q] & 0xffff0000u) * dd;
        }
    }
    int start = offs[c], end = offs[c + 1];
    for (int base = start; base < end; base += 16) {
        int m = end - base; if (m > 16) m = 16;
        int2 ed = (base + lane < end) ? edata[base + lane] : make_int2(0, 0);
        for (int j0 = 0; j0 < m; j0 += 4) {
#pragma unroll
            for (int jj = 0; jj < 4; ++jj) {
                int j = j0 + jj;
                int src = __shfl(ed.x, j, 16);
                float nrm = (j < m) ? __int_as_float(__shfl(ed.y, j, 16)) : 0.0f;
                uint4 v = xw4[(size_t)src * 16 + lane];
                unsigned w[4] = {v.x, v.y, v.z, v.w};
#pragma unroll
                for (int q = 0; q < 4; ++q) {
                    acc[2 * q]     += __uint_as_float(w[q] << 16) * nrm;
                    acc[2 * q + 1] += __uint_as_float(w[q] & 0xffff0000u) * nrm;
                }
            }
        }
    }
    float4 wla = ((const float4*)w_lin)[lane * 2];
    float4 wlb = ((const float4*)w_lin)[lane * 2 + 1];
    float r = fmaxf(acc[0], 0.0f) * wla.x + fmaxf(acc[1], 0.0f) * wla.y +
              fmaxf(acc[2], 0.0f) * wla.z + fmaxf(acc[3], 0.0f) * wla.w +
              fmaxf(acc[4], 0.0f) * wlb.x + fmaxf(acc[5], 0.0f) * wlb.y +
              fmaxf(acc[6], 0.0f) * wlb.z + fmaxf(acc[7], 0.0f) * wlb.w;
#pragma unroll
    for (int m = 8; m >= 1; m >>= 1) r += __shfl_xor(r, m, 16);
    if (lane == 0) out[c] = r + b_lin[0];
}

extern "C" void kernel_launch(void* const* d_in, const int* in_sizes, int n_in,
                              void* d_out, int out_size, void* d_ws, size_t ws_size,
                              hipStream_t stream) {
    const float* x     = (const float*)d_in[0];
    const int*   ei    = (const int*)d_in[1];
    const float* ew    = (const float*)d_in[2];
    const float* p     = (const float*)d_in[3];
    const float* W0    = (const float*)d_in[4];
    const float* w_ih  = (const float*)d_in[5];
    const float* w_hh  = (const float*)d_in[6];
    const float* b_ih  = (const float*)d_in[7];
    const float* b_hh  = (const float*)d_in[8];
    const float* w_lin = (const float*)d_in[9];
    const float* b_lin = (const float*)d_in[10];
    float* out = (float*)d_out;
    int n  = in_sizes[0] / DIM;
    int ne = in_sizes[2];
    (void)n_in; (void)out_size; (void)ws_size;

    char* base = (char*)d_ws;
    size_t o = 0;
    auto alloc = [&](size_t b) { size_t r = o; o += (b + 255) & ~(size_t)255; return r; };
    float*    score   = (float*)(base + alloc((size_t)n * 4));
    unsigned* hist    = (unsigned*)(base + alloc(65536 * 4));
    unsigned* counter = (unsigned*)(base + alloc(256));
    unsigned* binfo   = (unsigned*)(base + alloc(256));
    float*    cval    = (float*)(base + alloc((size_t)CAP * 4));
    int*      cidx    = (int*)(base + alloc((size_t)CAP * 4));
    int*      perm    = (int*)(base + alloc(TOPK * 4));
    float*    vals    = (float*)(base + alloc(TOPK * 4));
    float*    pinv    = (float*)(base + alloc(256));
    float*    Wm      = (float*)(base + alloc(DIM * DIM * 4));
    float*    dinv    = (float*)(base + alloc((size_t)n * 4));
    int*      cnt     = (int*)(base + alloc((size_t)n * 4));
    int*      offs    = (int*)(base + alloc((size_t)(n + 1) * 4));
    unsigned long long* packed = (unsigned long long*)(base + alloc((size_t)n * 8));
    int*      eseq    = (int*)(base + alloc((size_t)ne * 4));
    int*      bsum    = (int*)(base + alloc((SCAN_B + 1) * 4));
    int*      bbase   = (int*)(base + alloc((SCAN_B + 1) * 4));
    int2*     edata   = (int2*)(base + alloc((size_t)ne * 8));
    unsigned short* xwh = (unsigned short*)(base + alloc((size_t)n * DIM * 2));

    int zgrid = ((n > 65537 ? n : 65537) + 255) / 256;
    k_pnorm<<<1, DIM, 0, stream>>>(p, pinv);
    k_score<<<(n + 3) / 4, 256, 0, stream>>>(x, p, pinv, score, n);
    k_zero<<<zgrid, 256, 0, stream>>>(hist, counter, packed, n);
    k_hist<<<(n + 255) / 256, 256, 0, stream>>>(score, hist, n);
    k_findbin<<<1, 1024, 0, stream>>>(hist, binfo, TOPK);
    k_collect<<<(n + 255) / 256, 256, 0, stream>>>(score, binfo, counter, cval, cidx, n);
    k_rank<<<(CAP + 255) / 256, 256, 0, stream>>>(cval, cidx, counter, perm, vals, TOPK);
    k_gru<<<DIM, DIM, 0, stream>>>(x, perm, vals, W0, w_ih, w_hh, b_ih, b_hh, Wm);
    k_deg_cnt2<<<(ne + 255) / 256, 256, 0, stream>>>(ei, ew, packed, eseq, ne);
    k_dinv2<<<(n + 255) / 256, 256, 0, stream>>>(packed, dinv, cnt, n);
    k_scan1<<<SCAN_B, 256, 0, stream>>>(cnt, bsum, n);
    k_scan2<<<1, SCAN_B, 0, stream>>>(bsum, bbase);
    k_scan3<<<SCAN_B, 256, 0, stream>>>(cnt, bbase, offs, n);
    k_fill<<<(ne + 255) / 256, 256, 0, stream>>>(ei, ew, dinv, offs, eseq, edata, ne);
    dim3 gxw((n + 63) / 64, 2);
    k_xw<<<gxw, 256, 0, stream>>>(x, Wm, xwh, n);
    long long g_threads = (long long)n * 16;
    k_gather<<<(int)((g_threads + 255) / 256), 256, 0, stream>>>(
        xwh, dinv, offs, edata, w_lin, b_lin, out, n);
}

// Round 7
// 325.233 us; speedup vs baseline: 9.6725x; 1.0870x over previous
//
#include <hip/hip_runtime.h>
#include <hip/hip_bf16.h>
#include <math.h>

#define DIM 128
#define TOPK 128
#define CAP 4096
#define SCAN_B 256

__device__ __forceinline__ unsigned f2k(float f) {
    unsigned b = __float_as_uint(f);
    return (b & 0x80000000u) ? ~b : (b | 0x80000000u);
}

// round-to-nearest-even bf16 (as high 16 bits of fp32)
__device__ __forceinline__ unsigned bf16rn(float v) {
    unsigned u = __float_as_uint(v);
    u += 0x7fffu + ((u >> 16) & 1u);
    return u >> 16;
}

// one u64 atomic per edge: [63:40] count, [39:0] fixed-point weight sum (2^-32).
// returned old value gives this edge's per-destination sequence number.
__device__ __forceinline__ void deg_edge(const int* __restrict__ ei, const float* __restrict__ ew,
                                         unsigned long long* __restrict__ packed,
                                         int* __restrict__ eseq, int ne, int e) {
    int c = ei[ne + e];
    float w = ew[e];
    unsigned long long fx = (unsigned long long)((double)w * 4294967296.0);
    unsigned long long old = atomicAdd(&packed[c], (1ull << 40) | fx);
    eseq[e] = (int)(old >> 40);
}

// Bresenham interleave of degB deg-blocks among T total blocks.
__device__ __forceinline__ bool pick_deg(int bid, int degB, int T, int* mi, int* di) {
    long long a = (long long)bid * degB;
    int before = (int)(a / T);
    if ((int)((a + degB) / T) > before) { *di = before; return true; }
    *mi = bid - before;
    return false;
}

// block 0: ||p|| ; other blocks: zero packed degree accumulators
__global__ void k_pnorm_zero(const float* __restrict__ p, float* __restrict__ pinv,
                             unsigned long long* __restrict__ packed, int n) {
    if (blockIdx.x == 0) {
        __shared__ float s[DIM];
        int t = threadIdx.x;
        float v = p[t];
        s[t] = v * v;
        __syncthreads();
        for (int off = 64; off > 0; off >>= 1) {
            if (t < off) s[t] += s[t + off];
            __syncthreads();
        }
        if (t == 0) pinv[0] = 1.0f / sqrtf(s[0]);
    } else {
        int base = ((int)blockIdx.x - 1) * 1024 + (int)threadIdx.x;
#pragma unroll
        for (int j = 0; j < 8; ++j) {
            int i = base + j * 128;
            if (i < n) packed[i] = 0ull;
        }
    }
}

// wave per node score + deg slice
__global__ void k_score_deg(const float* __restrict__ x, const float* __restrict__ p,
                            const float* __restrict__ pinv, float* __restrict__ score, int n,
                            int degB, const int* __restrict__ ei, const float* __restrict__ ew,
                            unsigned long long* __restrict__ packed, int* __restrict__ eseq,
                            int e0, int e1, int ne) {
    int mi, di;
    if (pick_deg((int)blockIdx.x, degB, (int)gridDim.x, &mi, &di)) {
        int e = e0 + di * 256 + (int)threadIdx.x;
        if (e < e1) deg_edge(ei, ew, packed, eseq, ne, e);
        return;
    }
    int lane = threadIdx.x & 63;
    int node = mi * 4 + ((int)threadIdx.x >> 6);
    if (node >= n) return;
    const float2* x2 = (const float2*)(x) + (size_t)node * 64;
    const float2* p2 = (const float2*)p;
    float2 a = x2[lane], b = p2[lane];
    float acc = a.x * b.x + a.y * b.y;
#pragma unroll
    for (int m = 32; m >= 1; m >>= 1) acc += __shfl_xor(acc, m, 64);
    if (lane == 0) score[node] = acc * pinv[0];
}

// zero hist + counter, + deg slice
__global__ void k_zero_deg(unsigned* __restrict__ hist, unsigned* __restrict__ counter,
                           int degB, const int* __restrict__ ei, const float* __restrict__ ew,
                           unsigned long long* __restrict__ packed, int* __restrict__ eseq,
                           int e0, int e1, int ne) {
    int mi, di;
    if (pick_deg((int)blockIdx.x, degB, (int)gridDim.x, &mi, &di)) {
        int e = e0 + di * 256 + (int)threadIdx.x;
        if (e < e1) deg_edge(ei, ew, packed, eseq, ne, e);
        return;
    }
    int i = mi * 256 + (int)threadIdx.x;
    if (i < 65536) hist[i] = 0u;
    if (i == 0) counter[0] = 0u;
}

__global__ void k_hist(const float* __restrict__ score, unsigned* __restrict__ hist, int n) {
    int i = blockIdx.x * blockDim.x + threadIdx.x;
    if (i < n) atomicAdd(&hist[f2k(score[i]) >> 16], 1u);
}

// block 0: find threshold bin; other blocks: deg slice (1024 threads)
__global__ void k_findbin_deg(const unsigned* __restrict__ hist, unsigned* __restrict__ binfo, int k,
                              const int* __restrict__ ei, const float* __restrict__ ew,
                              unsigned long long* __restrict__ packed, int* __restrict__ eseq,
                              int e0, int e1, int ne) {
    if (blockIdx.x > 0) {
        int e = e0 + ((int)blockIdx.x - 1) * 1024 + (int)threadIdx.x;
        if (e < e1) deg_edge(ei, ew, packed, eseq, ne, e);
        return;
    }
    __shared__ unsigned csum[1024];
    int t = threadIdx.x;
    unsigned s = 0;
    for (int j = 0; j < 64; ++j) s += hist[t * 64 + j];
    csum[t] = s;
    __syncthreads();
    for (int off = 1; off < 1024; off <<= 1) {
        unsigned v = (t + off < 1024) ? csum[t + off] : 0u;
        __syncthreads();
        csum[t] += v;
        __syncthreads();
    }
    unsigned run = (t + 1 < 1024) ? csum[t + 1] : 0u;
    for (int j = 63; j >= 0; --j) {
        unsigned h = hist[t * 64 + j];
        if (h > 0u && run < (unsigned)k && run + h >= (unsigned)k) {
            binfo[0] = (unsigned)(t * 64 + j);
            binfo[1] = run;
        }
        run += h;
    }
}

__global__ void k_collect_deg(const float* __restrict__ score, const unsigned* __restrict__ binfo,
                              unsigned* __restrict__ counter, float* __restrict__ cval,
                              int* __restrict__ cidx, int n,
                              int degB, const int* __restrict__ ei, const float* __restrict__ ew,
                              unsigned long long* __restrict__ packed, int* __restrict__ eseq,
                              int e0, int e1, int ne) {
    int mi, di;
    if (pick_deg((int)blockIdx.x, degB, (int)gridDim.x, &mi, &di)) {
        int e = e0 + di * 256 + (int)threadIdx.x;
        if (e < e1) deg_edge(ei, ew, packed, eseq, ne, e);
        return;
    }
    int i = mi * 256 + (int)threadIdx.x;
    if (i >= n) return;
    float s = score[i];
    if ((f2k(s) >> 16) >= binfo[0]) {
        unsigned pos = atomicAdd(counter, 1u);
        if (pos < CAP) { cval[pos] = s; cidx[pos] = i; }
    }
}

// rank-based exact top-k (matches jax.lax.top_k: desc, lower index wins ties)
__global__ void k_rank_deg(const float* __restrict__ cval, const int* __restrict__ cidx,
                           const unsigned* __restrict__ counter, int* __restrict__ perm,
                           float* __restrict__ vals, int k,
                           int degB, const int* __restrict__ ei, const float* __restrict__ ew,
                           unsigned long long* __restrict__ packed, int* __restrict__ eseq,
                           int e0, int e1, int ne) {
    int mi, di;
    if (pick_deg((int)blockIdx.x, degB, (int)gridDim.x, &mi, &di)) {
        int e = e0 + di * 256 + (int)threadIdx.x;
        if (e < e1) deg_edge(ei, ew, packed, eseq, ne, e);
        return;
    }
    int i = mi * 256 + (int)threadIdx.x;
    unsigned cnt = counter[0];
    int m = (cnt < (unsigned)CAP) ? (int)cnt : CAP;
    if (i >= m) return;
    float v = cval[i]; int id = cidx[i];
    int rank = 0;
    for (int j = 0; j < m; ++j) {
        float vj = cval[j]; int ij = cidx[j];
        if (vj > v || (vj == v && ij < id)) ++rank;
    }
    if (rank < k) { perm[rank] = id; vals[rank] = v; }
}

// GRU with fused x_tilde + deg slice (128-thread blocks)
__global__ void k_gru_deg(const float* __restrict__ x, const int* __restrict__ perm,
                          const float* __restrict__ vals, const float* __restrict__ W0,
                          const float* __restrict__ w_ih, const float* __restrict__ w_hh,
                          const float* __restrict__ b_ih, const float* __restrict__ b_hh,
                          float* __restrict__ W,
                          int degB, const int* __restrict__ ei, const float* __restrict__ ew,
                          unsigned long long* __restrict__ packed, int* __restrict__ eseq,
                          int e0, int e1, int ne) {
    __shared__ float sx[DIM], sh[DIM];
    int mi, di;
    if (pick_deg((int)blockIdx.x, degB, (int)gridDim.x, &mi, &di)) {
        int e = e0 + di * 128 + (int)threadIdx.x;
        if (e < e1) deg_edge(ei, ew, packed, eseq, ne, e);
        return;
    }
    int i = mi, c = threadIdx.x;
    sx[c] = x[(size_t)perm[i] * DIM + c] * tanhf(vals[i]);
    sh[c] = W0[i * DIM + c];
    __syncthreads();
    float gr = b_ih[c], gz = b_ih[DIM + c], gn = b_ih[2 * DIM + c];
    float hr = b_hh[c], hz = b_hh[DIM + c], hn = b_hh[2 * DIM + c];
    const float* wr = w_ih + (size_t)c * DIM;
    const float* wz = w_ih + (size_t)(DIM + c) * DIM;
    const float* wn = w_ih + (size_t)(2 * DIM + c) * DIM;
    const float* ur = w_hh + (size_t)c * DIM;
    const float* uz = w_hh + (size_t)(DIM + c) * DIM;
    const float* un = w_hh + (size_t)(2 * DIM + c) * DIM;
    for (int d = 0; d < DIM; ++d) {
        float xd = sx[d], hd = sh[d];
        gr += xd * wr[d]; gz += xd * wz[d]; gn += xd * wn[d];
        hr += hd * ur[d]; hz += hd * uz[d]; hn += hd * un[d];
    }
    float r = 1.0f / (1.0f + expf(-(gr + hr)));
    float z = 1.0f / (1.0f + expf(-(gz + hz)));
    float nn = tanhf(gn + r * hn);
    W[i * DIM + c] = (1.0f - z) * nn + z * sh[c];
}

// xw = x @ W -> bf16 (64x64 tiles) interleaved with remaining deg edges
__global__ __launch_bounds__(256) void k_xw_deg(const float* __restrict__ x,
                                                const float* __restrict__ W,
                                                unsigned short* __restrict__ xwh, int n,
                                                int degB, const int* __restrict__ ei,
                                                const float* __restrict__ ew,
                                                unsigned long long* __restrict__ packed,
                                                int* __restrict__ eseq,
                                                int e0, int e1, int ne) {
    __shared__ float xsT[DIM * 64];  // [k][r]  32KB
    __shared__ float wls[DIM * 64];  // [k][c]  32KB
    int mi, di;
    if (pick_deg((int)blockIdx.x, degB, (int)gridDim.x, &mi, &di)) {
        int e = e0 + di * 256 + (int)threadIdx.x;
        if (e < e1) deg_edge(ei, ew, packed, eseq, ne, e);
        return;
    }
    int nTr = (n + 63) / 64;
    int r0 = (mi % nTr) * 64;
    int c0 = (mi / nTr) * 64;
    int t = threadIdx.x;
    const float4* W4 = (const float4*)W;
#pragma unroll
    for (int it = 0; it < 8; ++it) {
        int id = t + it * 256;
        int k = id >> 4, c4 = id & 15;
        float4 w = W4[k * 32 + (c0 >> 2) + c4];
        *((float4*)&wls[k * 64 + c4 * 4]) = w;
    }
#pragma unroll
    for (int it = 0; it < 8; ++it) {
        int id = t + it * 256;
        int r = id & 63, k4 = id >> 6;
        int row = r0 + r; if (row >= n) row = n - 1;
        float4 v = *((const float4*)&x[(size_t)row * DIM + k4 * 4]);
        xsT[(k4 * 4 + 0) * 64 + r] = v.x;
        xsT[(k4 * 4 + 1) * 64 + r] = v.y;
        xsT[(k4 * 4 + 2) * 64 + r] = v.z;
        xsT[(k4 * 4 + 3) * 64 + r] = v.w;
    }
    __syncthreads();
    int tc = t & 15, tr = t >> 4;
    float acc[4][4];
#pragma unroll
    for (int i = 0; i < 4; ++i)
#pragma unroll
        for (int j = 0; j < 4; ++j) acc[i][j] = 0.0f;
#pragma unroll 4
    for (int k = 0; k < DIM; ++k) {
        float4 xa = *((const float4*)&xsT[k * 64 + tr * 4]);
        float4 wa = *((const float4*)&wls[k * 64 + tc * 4]);
        float xv[4] = {xa.x, xa.y, xa.z, xa.w};
        float wv[4] = {wa.x, wa.y, wa.z, wa.w};
#pragma unroll
        for (int i = 0; i < 4; ++i)
#pragma unroll
            for (int j = 0; j < 4; ++j) acc[i][j] += xv[i] * wv[j];
    }
#pragma unroll
    for (int i = 0; i < 4; ++i) {
        int row = r0 + tr * 4 + i;
        if (row < n) {
            uint2 o;
            o.x = (bf16rn(acc[i][1]) << 16) | bf16rn(acc[i][0]);
            o.y = (bf16rn(acc[i][3]) << 16) | bf16rn(acc[i][2]);
            *((uint2*)&xwh[(size_t)row * DIM + c0 + tc * 4]) = o;
        }
    }
}

// unpack: dinv = rsqrt(1 + sum_w), cnt = in-count
__global__ void k_dinv2(const unsigned long long* __restrict__ packed,
                        float* __restrict__ dinv, int* __restrict__ cnt, int n) {
    int i = blockIdx.x * blockDim.x + threadIdx.x;
    if (i < n) {
        unsigned long long pk = packed[i];
        float sumw = (float)((double)(pk & ((1ull << 40) - 1ull)) * (1.0 / 4294967296.0));
        float deg = 1.0f + sumw;
        dinv[i] = rsqrtf(deg);
        cnt[i] = (int)(pk >> 40);
    }
}

// ---- 3-phase multi-block exclusive scan of cnt -> offs ----
__global__ void k_scan1(const int* __restrict__ cnt, int* __restrict__ bsum, int n) {
    __shared__ int red[256];
    int b = blockIdx.x, t = threadIdx.x;
    int chunk = (n + SCAN_B - 1) / SCAN_B;
    int lo = b * chunk;
    int hi = lo + chunk; if (hi > n) hi = n;
    int s = 0;
    for (int i = lo + t; i < hi; i += 256) s += cnt[i];
    red[t] = s;
    __syncthreads();
    for (int off = 128; off > 0; off >>= 1) {
        if (t < off) red[t] += red[t + off];
        __syncthreads();
    }
    if (t == 0) bsum[b] = red[0];
}

__global__ void k_scan2(const int* __restrict__ bsum, int* __restrict__ bbase) {
    __shared__ int s[SCAN_B];
    int t = threadIdx.x;
    s[t] = bsum[t];
    __syncthreads();
    for (int off = 1; off < SCAN_B; off <<= 1) {
        int v = (t >= off) ? s[t - off] : 0;
        __syncthreads();
        s[t] += v;
        __syncthreads();
    }
    bbase[t] = (t > 0) ? s[t - 1] : 0;
    if (t == SCAN_B - 1) bbase[SCAN_B] = s[SCAN_B - 1];
}

__global__ void k_scan3(const int* __restrict__ cnt, const int* __restrict__ bbase,
                        int* __restrict__ offs, int n) {
    __shared__ int red[256];
    int b = blockIdx.x, t = threadIdx.x;
    int chunk = (n + SCAN_B - 1) / SCAN_B;
    int lo = b * chunk;
    int hi = lo + chunk; if (hi > n) hi = n;
    int tchunk = (chunk + 255) / 256;
    int tlo = lo + t * tchunk;
    int thi = tlo + tchunk; if (thi > hi) thi = hi;
    int s = 0;
    for (int i = tlo; i < thi; ++i) s += cnt[i];
    red[t] = s;
    __syncthreads();
    for (int off = 1; off < 256; off <<= 1) {
        int v = (t >= off) ? red[t - off] : 0;
        __syncthreads();
        red[t] += v;
        __syncthreads();
    }
    int run = bbase[b] + ((t > 0) ? red[t - 1] : 0);
    for (int i = tlo; i < thi; ++i) {
        offs[i] = run; run += cnt[i];
    }
    if (b == 0 && t == 0) offs[n] = bbase[SCAN_B];
}

// bucket edges by destination, atomic-free: pos = offs[c] + eseq[e]
__global__ void k_fill(const int* __restrict__ ei, const float* __restrict__ ew,
                       const float* __restrict__ dinv, const int* __restrict__ offs,
                       const int* __restrict__ eseq, int2* __restrict__ edata, int ne) {
    int e = blockIdx.x * blockDim.x + threadIdx.x;
    if (e >= ne) return;
    int r = ei[e], c = ei[ne + e];
    float nrm = dinv[r] * ew[e] * dinv[c];
    int pos = offs[c] + eseq[e];
    edata[pos] = make_int2(r, __float_as_int(nrm));
}

// per-node gather + fused relu-linear head: 16 lanes per node, 8 bf16 (16B) each
__global__ __launch_bounds__(256) void k_gather(const unsigned short* __restrict__ xwh,
        const float* __restrict__ dinv, const int* __restrict__ offs,
        const int2* __restrict__ edata, const float* __restrict__ w_lin,
        const float* __restrict__ b_lin, float* __restrict__ out, int n) {
    int gid = blockIdx.x * 256 + threadIdx.x;
    int c = gid >> 4, lane = gid & 15;
    if (c >= n) return;
    const uint4* xw4 = (const uint4*)xwh;
    float dd = dinv[c]; dd *= dd;
    float acc[8];
    {
        uint4 a = xw4[(size_t)c * 16 + lane];
        unsigned w[4] = {a.x, a.y, a.z, a.w};
#pragma unroll
        for (int q = 0; q < 4; ++q) {
            acc[2 * q]     = __uint_as_float(w[q] << 16) * dd;
            acc[2 * q + 1] = __uint_as_float(w[q] & 0xffff0000u) * dd;
        }
    }
    int start = offs[c], end = offs[c + 1];
    for (int base = start; base < end; base += 16) {
        int m = end - base; if (m > 16) m = 16;
        int2 ed = (base + lane < end) ? edata[base + lane] : make_int2(0, 0);
        for (int j0 = 0; j0 < m; j0 += 4) {
#pragma unroll
            for (int jj = 0; jj < 4; ++jj) {
                int j = j0 + jj;
                int src = __shfl(ed.x, j, 16);
                float nrm = (j < m) ? __int_as_float(__shfl(ed.y, j, 16)) : 0.0f;
                uint4 v = xw4[(size_t)src * 16 + lane];
                unsigned w[4] = {v.x, v.y, v.z, v.w};
#pragma unroll
                for (int q = 0; q < 4; ++q) {
                    acc[2 * q]     += __uint_as_float(w[q] << 16) * nrm;
                    acc[2 * q + 1] += __uint_as_float(w[q] & 0xffff0000u) * nrm;
                }
            }
        }
    }
    float4 wla = ((const float4*)w_lin)[lane * 2];
    float4 wlb = ((const float4*)w_lin)[lane * 2 + 1];
    float r = fmaxf(acc[0], 0.0f) * wla.x + fmaxf(acc[1], 0.0f) * wla.y +
              fmaxf(acc[2], 0.0f) * wla.z + fmaxf(acc[3], 0.0f) * wla.w +
              fmaxf(acc[4], 0.0f) * wlb.x + fmaxf(acc[5], 0.0f) * wlb.y +
              fmaxf(acc[6], 0.0f) * wlb.z + fmaxf(acc[7], 0.0f) * wlb.w;
#pragma unroll
    for (int m = 8; m >= 1; m >>= 1) r += __shfl_xor(r, m, 16);
    if (lane == 0) out[c] = r + b_lin[0];
}

extern "C" void kernel_launch(void* const* d_in, const int* in_sizes, int n_in,
                              void* d_out, int out_size, void* d_ws, size_t ws_size,
                              hipStream_t stream) {
    const float* x     = (const float*)d_in[0];
    const int*   ei    = (const int*)d_in[1];
    const float* ew    = (const float*)d_in[2];
    const float* p     = (const float*)d_in[3];
    const float* W0    = (const float*)d_in[4];
    const float* w_ih  = (const float*)d_in[5];
    const float* w_hh  = (const float*)d_in[6];
    const float* b_ih  = (const float*)d_in[7];
    const float* b_hh  = (const float*)d_in[8];
    const float* w_lin = (const float*)d_in[9];
    const float* b_lin = (const float*)d_in[10];
    float* out = (float*)d_out;
    int n  = in_sizes[0] / DIM;
    int ne = in_sizes[2];
    (void)n_in; (void)out_size; (void)ws_size;

    char* base = (char*)d_ws;
    size_t o = 0;
    auto alloc = [&](size_t b) { size_t r = o; o += (b + 255) & ~(size_t)255; return r; };
    float*    score   = (float*)(base + alloc((size_t)n * 4));
    unsigned* hist    = (unsigned*)(base + alloc(65536 * 4));
    unsigned* counter = (unsigned*)(base + alloc(256));
    unsigned* binfo   = (unsigned*)(base + alloc(256));
    float*    cval    = (float*)(base + alloc((size_t)CAP * 4));
    int*      cidx    = (int*)(base + alloc((size_t)CAP * 4));
    int*      perm    = (int*)(base + alloc(TOPK * 4));
    float*    vals    = (float*)(base + alloc(TOPK * 4));
    float*    pinv    = (float*)(base + alloc(256));
    float*    Wm      = (float*)(base + alloc(DIM * DIM * 4));
    float*    dinv    = (float*)(base + alloc((size_t)n * 4));
    int*      cnt     = (int*)(base + alloc((size_t)n * 4));
    int*      offs    = (int*)(base + alloc((size_t)(n + 1) * 4));
    unsigned long long* packed = (unsigned long long*)(base + alloc((size_t)n * 8));
    int*      eseq    = (int*)(base + alloc((size_t)ne * 4));
    int*      bsum    = (int*)(base + alloc((SCAN_B + 1) * 4));
    int*      bbase   = (int*)(base + alloc((SCAN_B + 1) * 4));
    int2*     edata   = (int2*)(base + alloc((size_t)ne * 8));
    unsigned short* xwh = (unsigned short*)(base + alloc((size_t)n * DIM * 2));

    // edge-slice assignment: hide deg atomics under independent kernels
    struct Slice { int e0, e1, blocks; };
    int cur = 0;
    auto take = [&](int want, int bs) {
        Slice s; s.e0 = cur;
        int t = want; if (cur + t > ne) t = ne - cur;
        s.e1 = cur + t; cur = s.e1;
        s.blocks = (t + bs - 1) / bs;
        return s;
    };
    Slice sl_score = take(256000, 256);
    Slice sl_zero  = take(96000, 256);
    Slice sl_fb    = take(80000, 1024);
    Slice sl_col   = take(128000, 256);
    Slice sl_rank  = take(96000, 256);
    Slice sl_gru   = take(256000, 128);
    Slice sl_xw    = take(ne, 256);        // remainder

    int scoreMB = (n + 3) / 4;
    int colMB   = (n + 255) / 256;
    int xwMB    = ((n + 63) / 64) * 2;

    k_pnorm_zero<<<1 + (n + 1023) / 1024, 128, 0, stream>>>(p, pinv, packed, n);
    k_score_deg<<<scoreMB + sl_score.blocks, 256, 0, stream>>>(
        x, p, pinv, score, n, sl_score.blocks, ei, ew, packed, eseq, sl_score.e0, sl_score.e1, ne);
    k_zero_deg<<<256 + sl_zero.blocks, 256, 0, stream>>>(
        hist, counter, sl_zero.blocks, ei, ew, packed, eseq, sl_zero.e0, sl_zero.e1, ne);
    k_hist<<<(n + 255) / 256, 256, 0, stream>>>(score, hist, n);
    k_findbin_deg<<<1 + sl_fb.blocks, 1024, 0, stream>>>(
        hist, binfo, TOPK, ei, ew, packed, eseq, sl_fb.e0, sl_fb.e1, ne);
    k_collect_deg<<<colMB + sl_col.blocks, 256, 0, stream>>>(
        score, binfo, counter, cval, cidx, n, sl_col.blocks, ei, ew, packed, eseq,
        sl_col.e0, sl_col.e1, ne);
    k_rank_deg<<<(CAP / 256) + sl_rank.blocks, 256, 0, stream>>>(
        cval, cidx, counter, perm, vals, TOPK, sl_rank.blocks, ei, ew, packed, eseq,
        sl_rank.e0, sl_rank.e1, ne);
    k_gru_deg<<<DIM + sl_gru.blocks, 128, 0, stream>>>(
        x, perm, vals, W0, w_ih, w_hh, b_ih, b_hh, Wm, sl_gru.blocks, ei, ew, packed, eseq,
        sl_gru.e0, sl_gru.e1, ne);
    k_xw_deg<<<xwMB + sl_xw.blocks, 256, 0, stream>>>(
        x, Wm, xwh, n, sl_xw.blocks, ei, ew, packed, eseq, sl_xw.e0, sl_xw.e1, ne);
    k_dinv2<<<(n + 255) / 256, 256, 0, stream>>>(packed, dinv, cnt, n);
    k_scan1<<<SCAN_B, 256, 0, stream>>>(cnt, bsum, n);
    k_scan2<<<1, SCAN_B, 0, stream>>>(bsum, bbase);
    k_scan3<<<SCAN_B, 256, 0, stream>>>(cnt, bbase, offs, n);
    k_fill<<<(ne + 255) / 256, 256, 0, stream>>>(ei, ew, dinv, offs, eseq, edata, ne);
    long long g_threads = (long long)n * 16;
    k_gather<<<(int)((g_threads + 255) / 256), 256, 0, stream>>>(
        xwh, dinv, offs, edata, w_lin, b_lin, out, n);
}